// Round 1
// baseline (684.396 us; speedup 1.0000x reference)
//
#include <hip/hip_runtime.h>
#include <hip/hip_bf16.h>

#define T_STEPS 12
#define N_NODES 10000
#define FDIM 128
#define M_ROWS (T_STEPS * N_NODES)

// ---------------- CSR build (counting sort by dst) ----------------

__global__ __launch_bounds__(256) void k_count(const int* __restrict__ ei, int* __restrict__ cnt, int E) {
    int e = blockIdx.x * 256 + threadIdx.x;
    if (e < E) atomicAdd(&cnt[ei[E + e]], 1);
}

__global__ __launch_bounds__(1024) void k_scan(const int* __restrict__ cnt, int* __restrict__ rowptr,
                                               int* __restrict__ cursor) {
    __shared__ int buf[1024];
    __shared__ int base_s;
    int tid = threadIdx.x;
    if (tid == 0) base_s = 0;
    __syncthreads();
    for (int c0 = 0; c0 < N_NODES; c0 += 1024) {
        int i = c0 + tid;
        int x = (i < N_NODES) ? cnt[i] : 0;
        buf[tid] = x;
        __syncthreads();
        for (int off = 1; off < 1024; off <<= 1) {
            int v = (tid >= off) ? buf[tid - off] : 0;
            __syncthreads();
            buf[tid] += v;
            __syncthreads();
        }
        int excl = base_s + buf[tid] - x;
        if (i < N_NODES) { rowptr[i] = excl; cursor[i] = excl; }
        __syncthreads();
        if (tid == 0) base_s = base_s + buf[1023];
        __syncthreads();
    }
    if (tid == 0) rowptr[N_NODES] = base_s;
}

__global__ __launch_bounds__(256) void k_fill(const int* __restrict__ ei, const float* __restrict__ ew,
                                              int* __restrict__ cursor, int* __restrict__ col,
                                              float* __restrict__ val, int E) {
    int e = blockIdx.x * 256 + threadIdx.x;
    if (e < E) {
        int s = ei[e];
        int d = ei[E + e];
        int slot = atomicAdd(&cursor[d], 1);
        col[slot] = s;
        val[slot] = ew[e];
    }
}

__global__ __launch_bounds__(256) void k_dinv(const int* __restrict__ rowptr, const float* __restrict__ val,
                                              float* __restrict__ dinv) {
    int n = blockIdx.x * 256 + threadIdx.x;
    if (n < N_NODES) {
        int r0 = rowptr[n], r1 = rowptr[n + 1];
        float s = 0.f;
        for (int i = r0; i < r1; ++i) s += val[i];
        dinv[n] = (s > 0.f) ? rsqrtf(s) : 0.f;
    }
}

__global__ __launch_bounds__(256) void k_scale(const int* __restrict__ rowptr, const int* __restrict__ col,
                                               float* __restrict__ val, const float* __restrict__ dinv) {
    int n = blockIdx.x * 256 + threadIdx.x;
    if (n < N_NODES) {
        int r0 = rowptr[n], r1 = rowptr[n + 1];
        float dn = dinv[n];
        for (int i = r0; i < r1; ++i) val[i] = dn * val[i] * dinv[col[i]];
    }
}

// ---------------- f32 GEMM: C[M,128] = A[M,128] @ W[128,128] ----------------
// block: 256 threads (16 tx x 16 ty), tile 128 rows x 128 cols, 8x8 per thread.
// Cols per thread: {4tx..4tx+3} U {64+4tx..64+4tx+3} -> 2-way LDS access (free).
// LDS: As stored transposed [k][row] stride 132 -> conflict-free reads.

__global__ __launch_bounds__(256) void k_gemm(const float* __restrict__ A, const float* __restrict__ W,
                                              float* __restrict__ C, int Mrows) {
    __shared__ float As[32][132];
    __shared__ float Ws[32][132];
    int tid = threadIdx.x;
    int tx = tid & 15, ty = tid >> 4;
    int row0 = blockIdx.x * 128;
    float acc[8][8];
#pragma unroll
    for (int i = 0; i < 8; ++i)
#pragma unroll
        for (int j = 0; j < 8; ++j) acc[i][j] = 0.f;

    for (int k0 = 0; k0 < 128; k0 += 32) {
        // stage A (transpose to [k][row])
#pragma unroll
        for (int p = 0; p < 4; ++p) {
            int idx = tid + p * 256;
            int r = idx >> 3, kq = idx & 7;
            int gr = row0 + r;
            if (gr > Mrows - 1) gr = Mrows - 1;
            float4 v = *(const float4*)&A[(size_t)gr * FDIM + k0 + kq * 4];
            As[kq * 4 + 0][r] = v.x;
            As[kq * 4 + 1][r] = v.y;
            As[kq * 4 + 2][r] = v.z;
            As[kq * 4 + 3][r] = v.w;
        }
        // stage W ([k][col])
#pragma unroll
        for (int p = 0; p < 4; ++p) {
            int idx = tid + p * 256;
            int k = idx >> 5, cq = idx & 31;
            *(float4*)&Ws[k][cq * 4] = *(const float4*)&W[(size_t)(k0 + k) * FDIM + cq * 4];
        }
        __syncthreads();
#pragma unroll
        for (int k = 0; k < 32; ++k) {
            float a0[8], w0[8];
            *(float4*)&a0[0] = *(const float4*)&As[k][ty * 8];
            *(float4*)&a0[4] = *(const float4*)&As[k][ty * 8 + 4];
            *(float4*)&w0[0] = *(const float4*)&Ws[k][tx * 4];
            *(float4*)&w0[4] = *(const float4*)&Ws[k][64 + tx * 4];
#pragma unroll
            for (int i = 0; i < 8; ++i)
#pragma unroll
                for (int j = 0; j < 8; ++j) acc[i][j] = fmaf(a0[i], w0[j], acc[i][j]);
        }
        __syncthreads();
    }
#pragma unroll
    for (int i = 0; i < 8; ++i) {
        int r = row0 + ty * 8 + i;
        if (r < Mrows) {
            float4 o0 = make_float4(acc[i][0], acc[i][1], acc[i][2], acc[i][3]);
            float4 o1 = make_float4(acc[i][4], acc[i][5], acc[i][6], acc[i][7]);
            *(float4*)&C[(size_t)r * FDIM + tx * 4] = o0;
            *(float4*)&C[(size_t)r * FDIM + 64 + tx * 4] = o1;
        }
    }
}

// ---------------- spatial aggregation: out[t][n][:] = bias + sum val*S[t][col][:] ----------------

__global__ __launch_bounds__(128) void k_agg(const float* __restrict__ S, const int* __restrict__ rowptr,
                                             const int* __restrict__ col, const float* __restrict__ val,
                                             const float* __restrict__ bias, float* __restrict__ out,
                                             int do_relu) {
    int n = blockIdx.x;
    int t = blockIdx.y;
    int c = threadIdx.x;
    int r0 = rowptr[n], r1 = rowptr[n + 1];
    const float* St = S + (size_t)t * N_NODES * FDIM;
    float acc = 0.f;
    for (int i = r0; i < r1; ++i) {
        acc += val[i] * St[(size_t)col[i] * FDIM + c];
    }
    float o = acc + bias[c];
    if (do_relu) o = fmaxf(o, 0.f);
    out[((size_t)t * N_NODES + n) * FDIM + c] = o;
}

// ---------------- temporal aggregation (chain graph, closed-form norm) ----------------
// mode 1: relu(agg + bias); mode 2: tanh(agg + bias). In-place-safe per thread.

__global__ __launch_bounds__(256) void k_tagg(const float* __restrict__ S, const float* __restrict__ bias,
                                              float* __restrict__ out, int mode) {
    int idx = blockIdx.x * 256 + threadIdx.x;
    if (idx >= N_NODES * FDIM) return;
    int c = idx & (FDIM - 1);
    float s[T_STEPS];
#pragma unroll
    for (int t = 0; t < T_STEPS; ++t) s[t] = S[(size_t)t * N_NODES * FDIM + idx];
    float b = bias[c];
    const float IS2 = 0.70710678118654752f;
#pragma unroll
    for (int t = 0; t < T_STEPS; ++t) {
        float dt = (t == 0 || t == T_STEPS - 1) ? 1.f : IS2;
        float a = 0.f;
        if (t > 0) {
            float dp = (t - 1 == 0) ? 1.f : IS2;
            a += dp * s[t - 1];
        }
        if (t < T_STEPS - 1) {
            float dn = (t + 1 == T_STEPS - 1) ? 1.f : IS2;
            a += dn * s[t + 1];
        }
        float o = dt * a + b;
        if (mode == 1) o = fmaxf(o, 0.f);
        else o = tanhf(o);
        out[(size_t)t * N_NODES * FDIM + idx] = o;
    }
}

// ---------------- launch ----------------

extern "C" void kernel_launch(void* const* d_in, const int* in_sizes, int n_in,
                              void* d_out, int out_size, void* d_ws, size_t ws_size,
                              hipStream_t stream) {
    const float* x   = (const float*)d_in[0];
    const int*   ei  = (const int*)d_in[1];
    const float* ew  = (const float*)d_in[2];
    const float* W1  = (const float*)d_in[3];
    const float* b1  = (const float*)d_in[4];
    const float* W2  = (const float*)d_in[5];
    const float* b2  = (const float*)d_in[6];
    const float* Wt1 = (const float*)d_in[7];
    const float* bt1 = (const float*)d_in[8];
    const float* Wt2 = (const float*)d_in[9];
    const float* bt2 = (const float*)d_in[10];
    float* S = (float*)d_out;  // f32 GEMM outputs live in d_out
    const int E = in_sizes[2];

    char* w = (char*)d_ws;
    float* bufA  = (float*)w;
    size_t off   = (size_t)M_ROWS * FDIM * 4;
    int* cnt     = (int*)(w + off); off += (size_t)N_NODES * 4;
    int* rowptr  = (int*)(w + off); off += (size_t)(N_NODES + 1) * 4;
    int* cursor  = (int*)(w + off); off += (size_t)N_NODES * 4;
    int* col     = (int*)(w + off); off += (size_t)E * 4;
    float* val   = (float*)(w + off); off += (size_t)E * 4;
    float* dinv  = (float*)(w + off); off += (size_t)N_NODES * 4;

    hipMemsetAsync(cnt, 0, (size_t)N_NODES * 4, stream);
    int eb = (E + 255) / 256;
    int nb = (N_NODES + 255) / 256;
    k_count<<<eb, 256, 0, stream>>>(ei, cnt, E);
    k_scan<<<1, 1024, 0, stream>>>(cnt, rowptr, cursor);
    k_fill<<<eb, 256, 0, stream>>>(ei, ew, cursor, col, val, E);
    k_dinv<<<nb, 256, 0, stream>>>(rowptr, val, dinv);
    k_scale<<<nb, 256, 0, stream>>>(rowptr, col, val, dinv);

    int gb = (M_ROWS + 127) / 128;
    dim3 aggGrid(N_NODES, T_STEPS);
    int tb = (N_NODES * FDIM + 255) / 256;

    // spatial layer 1: S = X@W1 ; bufA = relu(A*S + b1)
    k_gemm<<<gb, 256, 0, stream>>>(x, W1, S, M_ROWS);
    k_agg<<<aggGrid, 128, 0, stream>>>(S, rowptr, col, val, b1, bufA, 1);
    // spatial layer 2: S = bufA@W2 ; bufA = A*S + b2
    k_gemm<<<gb, 256, 0, stream>>>(bufA, W2, S, M_ROWS);
    k_agg<<<aggGrid, 128, 0, stream>>>(S, rowptr, col, val, b2, bufA, 0);
    // temporal layer 1: S = bufA@Wt1 ; bufA = relu(Tagg(S) + bt1)
    k_gemm<<<gb, 256, 0, stream>>>(bufA, Wt1, S, M_ROWS);
    k_tagg<<<tb, 256, 0, stream>>>(S, bt1, bufA, 1);
    // temporal layer 2: S = bufA@Wt2 ; out = tanh(Tagg(S) + bt2)  (in-place on d_out)
    k_gemm<<<gb, 256, 0, stream>>>(bufA, Wt2, S, M_ROWS);
    k_tagg<<<tb, 256, 0, stream>>>(S, bt2, S, 2);
}

// Round 2
// 594.154 us; speedup vs baseline: 1.1519x; 1.1519x over previous
//
#include <hip/hip_runtime.h>
#include <hip/hip_bf16.h>

#define T_STEPS 12
#define N_NODES 10000
#define FDIM 128
#define M_ROWS (T_STEPS * N_NODES)

// ---------------- CSR build (counting sort by dst) ----------------

__global__ __launch_bounds__(256) void k_count(const int* __restrict__ ei, int* __restrict__ cnt, int E) {
    int e = blockIdx.x * 256 + threadIdx.x;
    if (e < E) atomicAdd(&cnt[ei[E + e]], 1);
}

__global__ __launch_bounds__(1024) void k_scan(const int* __restrict__ cnt, int* __restrict__ rowptr,
                                               int* __restrict__ cursor) {
    __shared__ int buf[1024];
    __shared__ int base_s;
    int tid = threadIdx.x;
    if (tid == 0) base_s = 0;
    __syncthreads();
    for (int c0 = 0; c0 < N_NODES; c0 += 1024) {
        int i = c0 + tid;
        int x = (i < N_NODES) ? cnt[i] : 0;
        buf[tid] = x;
        __syncthreads();
        for (int off = 1; off < 1024; off <<= 1) {
            int v = (tid >= off) ? buf[tid - off] : 0;
            __syncthreads();
            buf[tid] += v;
            __syncthreads();
        }
        int excl = base_s + buf[tid] - x;
        if (i < N_NODES) { rowptr[i] = excl; cursor[i] = excl; }
        __syncthreads();
        if (tid == 0) base_s = base_s + buf[1023];
        __syncthreads();
    }
    if (tid == 0) rowptr[N_NODES] = base_s;
}

__global__ __launch_bounds__(256) void k_fill(const int* __restrict__ ei, const float* __restrict__ ew,
                                              int* __restrict__ cursor, int* __restrict__ col,
                                              float* __restrict__ val, int E) {
    int e = blockIdx.x * 256 + threadIdx.x;
    if (e < E) {
        int s = ei[e];
        int d = ei[E + e];
        int slot = atomicAdd(&cursor[d], 1);
        col[slot] = s;
        val[slot] = ew[e];
    }
}

__global__ __launch_bounds__(256) void k_dinv(const int* __restrict__ rowptr, const float* __restrict__ val,
                                              float* __restrict__ dinv) {
    int n = blockIdx.x * 256 + threadIdx.x;
    if (n < N_NODES) {
        int r0 = rowptr[n], r1 = rowptr[n + 1];
        float s = 0.f;
        for (int i = r0; i < r1; ++i) s += val[i];
        dinv[n] = (s > 0.f) ? rsqrtf(s) : 0.f;
    }
}

__global__ __launch_bounds__(256) void k_scale(const int* __restrict__ rowptr, const int* __restrict__ col,
                                               float* __restrict__ val, const float* __restrict__ dinv) {
    int n = blockIdx.x * 256 + threadIdx.x;
    if (n < N_NODES) {
        int r0 = rowptr[n], r1 = rowptr[n + 1];
        float dn = dinv[n];
        for (int i = r0; i < r1; ++i) val[i] = dn * val[i] * dinv[col[i]];
    }
}

// ---------------- f32 GEMM: C[M,128] = A[M,128] @ W[128,128] ----------------

__global__ __launch_bounds__(256) void k_gemm(const float* __restrict__ A, const float* __restrict__ W,
                                              float* __restrict__ C, int Mrows) {
    __shared__ float As[32][132];
    __shared__ float Ws[32][132];
    int tid = threadIdx.x;
    int tx = tid & 15, ty = tid >> 4;
    int row0 = blockIdx.x * 128;
    float acc[8][8];
#pragma unroll
    for (int i = 0; i < 8; ++i)
#pragma unroll
        for (int j = 0; j < 8; ++j) acc[i][j] = 0.f;

    for (int k0 = 0; k0 < 128; k0 += 32) {
#pragma unroll
        for (int p = 0; p < 4; ++p) {
            int idx = tid + p * 256;
            int r = idx >> 3, kq = idx & 7;
            int gr = row0 + r;
            if (gr > Mrows - 1) gr = Mrows - 1;
            float4 v = *(const float4*)&A[(size_t)gr * FDIM + k0 + kq * 4];
            As[kq * 4 + 0][r] = v.x;
            As[kq * 4 + 1][r] = v.y;
            As[kq * 4 + 2][r] = v.z;
            As[kq * 4 + 3][r] = v.w;
        }
#pragma unroll
        for (int p = 0; p < 4; ++p) {
            int idx = tid + p * 256;
            int k = idx >> 5, cq = idx & 31;
            *(float4*)&Ws[k][cq * 4] = *(const float4*)&W[(size_t)(k0 + k) * FDIM + cq * 4];
        }
        __syncthreads();
#pragma unroll
        for (int k = 0; k < 32; ++k) {
            float a0[8], w0[8];
            *(float4*)&a0[0] = *(const float4*)&As[k][ty * 8];
            *(float4*)&a0[4] = *(const float4*)&As[k][ty * 8 + 4];
            *(float4*)&w0[0] = *(const float4*)&Ws[k][tx * 4];
            *(float4*)&w0[4] = *(const float4*)&Ws[k][64 + tx * 4];
#pragma unroll
            for (int i = 0; i < 8; ++i)
#pragma unroll
                for (int j = 0; j < 8; ++j) acc[i][j] = fmaf(a0[i], w0[j], acc[i][j]);
        }
        __syncthreads();
    }
#pragma unroll
    for (int i = 0; i < 8; ++i) {
        int r = row0 + ty * 8 + i;
        if (r < Mrows) {
            float4 o0 = make_float4(acc[i][0], acc[i][1], acc[i][2], acc[i][3]);
            float4 o1 = make_float4(acc[i][4], acc[i][5], acc[i][6], acc[i][7]);
            *(float4*)&C[(size_t)r * FDIM + tx * 4] = o0;
            *(float4*)&C[(size_t)r * FDIM + 64 + tx * 4] = o1;
        }
    }
}

// ---------------- spatial aggregation, ALL 12 time steps per block ----------------
// block = one node n, 128 threads (one per feature). Per edge: col/val are
// wave-uniform (scalar loads); 12 independent row-gathers (stride 5.12 MB)
// feed 12 accumulators -> 12-way memory-level parallelism per iteration.

__global__ __launch_bounds__(128) void k_agg12(const float* __restrict__ S, const int* __restrict__ rowptr,
                                               const int* __restrict__ col, const float* __restrict__ val,
                                               const float* __restrict__ bias, float* __restrict__ out,
                                               int do_relu) {
    int n = blockIdx.x;
    int c = threadIdx.x;
    int r0 = rowptr[n], r1 = rowptr[n + 1];
    float acc[T_STEPS];
#pragma unroll
    for (int t = 0; t < T_STEPS; ++t) acc[t] = 0.f;

    for (int i = r0; i < r1; ++i) {
        int cl = col[i];
        float v = val[i];
        const float* Sp = S + (size_t)cl * FDIM + c;
#pragma unroll
        for (int t = 0; t < T_STEPS; ++t)
            acc[t] = fmaf(v, Sp[(size_t)t * N_NODES * FDIM], acc[t]);
    }

    float b = bias[c];
#pragma unroll
    for (int t = 0; t < T_STEPS; ++t) {
        float o = acc[t] + b;
        if (do_relu) o = fmaxf(o, 0.f);
        out[((size_t)t * N_NODES + n) * FDIM + c] = o;
    }
}

// ---------------- temporal aggregation (chain graph, closed-form norm) ----------------

__global__ __launch_bounds__(256) void k_tagg(const float* __restrict__ S, const float* __restrict__ bias,
                                              float* __restrict__ out, int mode) {
    int idx = blockIdx.x * 256 + threadIdx.x;
    if (idx >= N_NODES * FDIM) return;
    int c = idx & (FDIM - 1);
    float s[T_STEPS];
#pragma unroll
    for (int t = 0; t < T_STEPS; ++t) s[t] = S[(size_t)t * N_NODES * FDIM + idx];
    float b = bias[c];
    const float IS2 = 0.70710678118654752f;
#pragma unroll
    for (int t = 0; t < T_STEPS; ++t) {
        float dt = (t == 0 || t == T_STEPS - 1) ? 1.f : IS2;
        float a = 0.f;
        if (t > 0) {
            float dp = (t - 1 == 0) ? 1.f : IS2;
            a += dp * s[t - 1];
        }
        if (t < T_STEPS - 1) {
            float dn = (t + 1 == T_STEPS - 1) ? 1.f : IS2;
            a += dn * s[t + 1];
        }
        float o = dt * a + b;
        if (mode == 1) o = fmaxf(o, 0.f);
        else o = tanhf(o);
        out[(size_t)t * N_NODES * FDIM + idx] = o;
    }
}

// ---------------- launch ----------------

extern "C" void kernel_launch(void* const* d_in, const int* in_sizes, int n_in,
                              void* d_out, int out_size, void* d_ws, size_t ws_size,
                              hipStream_t stream) {
    const float* x   = (const float*)d_in[0];
    const int*   ei  = (const int*)d_in[1];
    const float* ew  = (const float*)d_in[2];
    const float* W1  = (const float*)d_in[3];
    const float* b1  = (const float*)d_in[4];
    const float* W2  = (const float*)d_in[5];
    const float* b2  = (const float*)d_in[6];
    const float* Wt1 = (const float*)d_in[7];
    const float* bt1 = (const float*)d_in[8];
    const float* Wt2 = (const float*)d_in[9];
    const float* bt2 = (const float*)d_in[10];
    float* S = (float*)d_out;  // f32 GEMM outputs live in d_out
    const int E = in_sizes[2];

    char* w = (char*)d_ws;
    float* bufA  = (float*)w;
    size_t off   = (size_t)M_ROWS * FDIM * 4;
    int* cnt     = (int*)(w + off); off += (size_t)N_NODES * 4;
    int* rowptr  = (int*)(w + off); off += (size_t)(N_NODES + 1) * 4;
    int* cursor  = (int*)(w + off); off += (size_t)N_NODES * 4;
    int* col     = (int*)(w + off); off += (size_t)E * 4;
    float* val   = (float*)(w + off); off += (size_t)E * 4;
    float* dinv  = (float*)(w + off); off += (size_t)N_NODES * 4;

    hipMemsetAsync(cnt, 0, (size_t)N_NODES * 4, stream);
    int eb = (E + 255) / 256;
    int nb = (N_NODES + 255) / 256;
    k_count<<<eb, 256, 0, stream>>>(ei, cnt, E);
    k_scan<<<1, 1024, 0, stream>>>(cnt, rowptr, cursor);
    k_fill<<<eb, 256, 0, stream>>>(ei, ew, cursor, col, val, E);
    k_dinv<<<nb, 256, 0, stream>>>(rowptr, val, dinv);
    k_scale<<<nb, 256, 0, stream>>>(rowptr, col, val, dinv);

    int gb = (M_ROWS + 127) / 128;
    int tb = (N_NODES * FDIM + 255) / 256;

    // spatial layer 1: S = X@W1 ; bufA = relu(A*S + b1)
    k_gemm<<<gb, 256, 0, stream>>>(x, W1, S, M_ROWS);
    k_agg12<<<N_NODES, 128, 0, stream>>>(S, rowptr, col, val, b1, bufA, 1);
    // spatial layer 2: S = bufA@W2 ; bufA = A*S + b2
    k_gemm<<<gb, 256, 0, stream>>>(bufA, W2, S, M_ROWS);
    k_agg12<<<N_NODES, 128, 0, stream>>>(S, rowptr, col, val, b2, bufA, 0);
    // temporal layer 1: S = bufA@Wt1 ; bufA = relu(Tagg(S) + bt1)
    k_gemm<<<gb, 256, 0, stream>>>(bufA, Wt1, S, M_ROWS);
    k_tagg<<<tb, 256, 0, stream>>>(S, bt1, bufA, 1);
    // temporal layer 2: S = bufA@Wt2 ; out = tanh(Tagg(S) + bt2)  (in-place on d_out)
    k_gemm<<<gb, 256, 0, stream>>>(bufA, Wt2, S, M_ROWS);
    k_tagg<<<tb, 256, 0, stream>>>(S, bt2, S, 2);
}

// Round 3
// 527.581 us; speedup vs baseline: 1.2972x; 1.1262x over previous
//
#include <hip/hip_runtime.h>
#include <hip/hip_bf16.h>

#define T_STEPS 12
#define N_NODES 10000
#define FDIM 128
#define M_ROWS (T_STEPS * N_NODES)

typedef __attribute__((ext_vector_type(8))) short short8v;
typedef __attribute__((ext_vector_type(4))) float f32x4;

// ---------------- CSR build (counting sort by dst) ----------------

__global__ __launch_bounds__(256) void k_count(const int* __restrict__ ei, int* __restrict__ cnt, int E) {
    int e = blockIdx.x * 256 + threadIdx.x;
    if (e < E) atomicAdd(&cnt[ei[E + e]], 1);
}

__global__ __launch_bounds__(1024) void k_scan(const int* __restrict__ cnt, int* __restrict__ rowptr,
                                               int* __restrict__ cursor) {
    __shared__ int buf[1024];
    __shared__ int base_s;
    int tid = threadIdx.x;
    if (tid == 0) base_s = 0;
    __syncthreads();
    for (int c0 = 0; c0 < N_NODES; c0 += 1024) {
        int i = c0 + tid;
        int x = (i < N_NODES) ? cnt[i] : 0;
        buf[tid] = x;
        __syncthreads();
        for (int off = 1; off < 1024; off <<= 1) {
            int v = (tid >= off) ? buf[tid - off] : 0;
            __syncthreads();
            buf[tid] += v;
            __syncthreads();
        }
        int excl = base_s + buf[tid] - x;
        if (i < N_NODES) { rowptr[i] = excl; cursor[i] = excl; }
        __syncthreads();
        if (tid == 0) base_s = base_s + buf[1023];
        __syncthreads();
    }
    if (tid == 0) rowptr[N_NODES] = base_s;
}

__global__ __launch_bounds__(256) void k_fill(const int* __restrict__ ei, const float* __restrict__ ew,
                                              int* __restrict__ cursor, int* __restrict__ col,
                                              float* __restrict__ val, int E) {
    int e = blockIdx.x * 256 + threadIdx.x;
    if (e < E) {
        int s = ei[e];
        int d = ei[E + e];
        int slot = atomicAdd(&cursor[d], 1);
        col[slot] = s;
        val[slot] = ew[e];
    }
}

__global__ __launch_bounds__(256) void k_dinv(const int* __restrict__ rowptr, const float* __restrict__ val,
                                              float* __restrict__ dinv) {
    int n = blockIdx.x * 256 + threadIdx.x;
    if (n < N_NODES) {
        int r0 = rowptr[n], r1 = rowptr[n + 1];
        float s = 0.f;
        for (int i = r0; i < r1; ++i) s += val[i];
        dinv[n] = (s > 0.f) ? rsqrtf(s) : 0.f;
    }
}

__global__ __launch_bounds__(256) void k_scale(const int* __restrict__ rowptr, const int* __restrict__ col,
                                               float* __restrict__ val, const float* __restrict__ dinv) {
    int n = blockIdx.x * 256 + threadIdx.x;
    if (n < N_NODES) {
        int r0 = rowptr[n], r1 = rowptr[n + 1];
        float dn = dinv[n];
        for (int i = r0; i < r1; ++i) val[i] = dn * val[i] * dinv[col[i]];
    }
}

// ---------------- bf16 split helpers ----------------

__device__ __forceinline__ short bf16_rne(float x) {
    unsigned u = __builtin_bit_cast(unsigned, x);
    return (short)((u + 0x7fffu + ((u >> 16) & 1u)) >> 16);
}
__device__ __forceinline__ void split2(float x, short& hi, short& lo) {
    unsigned u = __builtin_bit_cast(unsigned, x);
    unsigned hb = (u + 0x7fffu + ((u >> 16) & 1u)) & 0xffff0000u;
    hi = (short)(hb >> 16);
    float r = x - __builtin_bit_cast(float, hb);
    lo = bf16_rne(r);
}

// Pre-split W [128k][128n] f32 -> hi/lo bf16 in MFMA B-fragment layout:
// out[((s*4+kb)*128 + col)*8 + j] = W[(s*32 + kb*8 + j)][col]
__global__ __launch_bounds__(256) void k_wsplit(const float* __restrict__ W,
                                                short* __restrict__ Whf, short* __restrict__ Wlf) {
    int idx = blockIdx.x * 256 + threadIdx.x;  // 16384
    int k = idx >> 7, col = idx & 127;
    int s = k >> 5, kb = (k >> 3) & 3, j = k & 7;
    short hi, lo;
    split2(W[(size_t)k * FDIM + col], hi, lo);
    size_t oi = (size_t)(((s * 4 + kb) * 128 + col)) * 8 + j;
    Whf[oi] = hi;
    Wlf[oi] = lo;
}

// ---------------- split-bf16 MFMA GEMM: C[M,128] = A[M,128] @ W[128,128] ----------------
// 256 threads = 4 waves; wave owns 32 rows x 128 cols (2 m-tiles x 8 n-tiles of 16x16).
// A fragments loaded straight from global f32 and split hi/lo in-register.
// W fragments from pre-split frag-layout buffers (L2-resident, 32 KB each).
// C = Ahi*Whi + Ahi*Wlo + Alo*Whi  (error ~2^-17, threshold 8.8e-3).

__global__ __launch_bounds__(256) void k_gemm_mfma(const float* __restrict__ A,
                                                   const short* __restrict__ Whf,
                                                   const short* __restrict__ Wlf,
                                                   float* __restrict__ C, int Mrows) {
    int tid = threadIdx.x;
    int wave = tid >> 6, lane = tid & 63;
    int lr = lane & 15, kb = lane >> 4;
    int rbase = blockIdx.x * 128 + wave * 32;

    f32x4 acc[2][8];
#pragma unroll
    for (int m = 0; m < 2; ++m)
#pragma unroll
        for (int n = 0; n < 8; ++n) acc[m][n] = (f32x4){0.f, 0.f, 0.f, 0.f};

#pragma unroll
    for (int s = 0; s < 4; ++s) {
        short8v ah[2], al[2];
#pragma unroll
        for (int m = 0; m < 2; ++m) {
            int r = rbase + m * 16 + lr;
            if (r > Mrows - 1) r = Mrows - 1;
            const float* ap = &A[(size_t)r * FDIM + s * 32 + kb * 8];
            float4 x0 = *(const float4*)ap;
            float4 x1 = *(const float4*)(ap + 4);
            float xs[8] = {x0.x, x0.y, x0.z, x0.w, x1.x, x1.y, x1.z, x1.w};
#pragma unroll
            for (int j = 0; j < 8; ++j) {
                short hi, lo;
                split2(xs[j], hi, lo);
                ah[m][j] = hi;
                al[m][j] = lo;
            }
        }
#pragma unroll
        for (int n = 0; n < 8; ++n) {
            size_t wo = (size_t)(((s * 4 + kb) * 128 + n * 16 + lr)) * 8;
            short8v wh = *(const short8v*)&Whf[wo];
            short8v wl = *(const short8v*)&Wlf[wo];
#pragma unroll
            for (int m = 0; m < 2; ++m) {
                acc[m][n] = __builtin_amdgcn_mfma_f32_16x16x32_bf16(ah[m], wh, acc[m][n], 0, 0, 0);
                acc[m][n] = __builtin_amdgcn_mfma_f32_16x16x32_bf16(ah[m], wl, acc[m][n], 0, 0, 0);
                acc[m][n] = __builtin_amdgcn_mfma_f32_16x16x32_bf16(al[m], wh, acc[m][n], 0, 0, 0);
            }
        }
    }
    // D layout: col = lane&15 (+16n), row = rbase + 16m + (lane>>4)*4 + q
#pragma unroll
    for (int m = 0; m < 2; ++m)
#pragma unroll
        for (int q = 0; q < 4; ++q) {
            int r = rbase + m * 16 + kb * 4 + q;
            if (r < Mrows) {
#pragma unroll
                for (int n = 0; n < 8; ++n)
                    C[(size_t)r * FDIM + n * 16 + lr] = acc[m][n][q];
            }
        }
}

// ---------------- spatial aggregation, ALL 12 time steps per block, edges x2 ----------------

__global__ __launch_bounds__(128) void k_agg12(const float* __restrict__ S, const int* __restrict__ rowptr,
                                               const int* __restrict__ col, const float* __restrict__ val,
                                               const float* __restrict__ bias, float* __restrict__ out,
                                               int do_relu) {
    int n = blockIdx.x;
    int c = threadIdx.x;
    int r0 = rowptr[n], r1 = rowptr[n + 1];
    float acc[T_STEPS];
#pragma unroll
    for (int t = 0; t < T_STEPS; ++t) acc[t] = 0.f;

    int i = r0;
    for (; i + 2 <= r1; i += 2) {
        int c0 = col[i], c1 = col[i + 1];
        float v0 = val[i], v1 = val[i + 1];
        const float* S0 = S + (size_t)c0 * FDIM + c;
        const float* S1 = S + (size_t)c1 * FDIM + c;
#pragma unroll
        for (int t = 0; t < T_STEPS; ++t) {
            float x0 = S0[(size_t)t * N_NODES * FDIM];
            float x1 = S1[(size_t)t * N_NODES * FDIM];
            acc[t] = fmaf(v0, x0, fmaf(v1, x1, acc[t]));
        }
    }
    if (i < r1) {
        int c0 = col[i];
        float v0 = val[i];
        const float* S0 = S + (size_t)c0 * FDIM + c;
#pragma unroll
        for (int t = 0; t < T_STEPS; ++t)
            acc[t] = fmaf(v0, S0[(size_t)t * N_NODES * FDIM], acc[t]);
    }

    float b = bias[c];
#pragma unroll
    for (int t = 0; t < T_STEPS; ++t) {
        float o = acc[t] + b;
        if (do_relu) o = fmaxf(o, 0.f);
        out[((size_t)t * N_NODES + n) * FDIM + c] = o;
    }
}

// ---------------- temporal aggregation (chain graph, closed-form norm) ----------------

__global__ __launch_bounds__(256) void k_tagg(const float* __restrict__ S, const float* __restrict__ bias,
                                              float* __restrict__ out, int mode) {
    int idx = blockIdx.x * 256 + threadIdx.x;
    if (idx >= N_NODES * FDIM) return;
    int c = idx & (FDIM - 1);
    float s[T_STEPS];
#pragma unroll
    for (int t = 0; t < T_STEPS; ++t) s[t] = S[(size_t)t * N_NODES * FDIM + idx];
    float b = bias[c];
    const float IS2 = 0.70710678118654752f;
#pragma unroll
    for (int t = 0; t < T_STEPS; ++t) {
        float dt = (t == 0 || t == T_STEPS - 1) ? 1.f : IS2;
        float a = 0.f;
        if (t > 0) {
            float dp = (t - 1 == 0) ? 1.f : IS2;
            a += dp * s[t - 1];
        }
        if (t < T_STEPS - 1) {
            float dn = (t + 1 == T_STEPS - 1) ? 1.f : IS2;
            a += dn * s[t + 1];
        }
        float o = dt * a + b;
        if (mode == 1) o = fmaxf(o, 0.f);
        else o = tanhf(o);
        out[(size_t)t * N_NODES * FDIM + idx] = o;
    }
}

// ---------------- launch ----------------

extern "C" void kernel_launch(void* const* d_in, const int* in_sizes, int n_in,
                              void* d_out, int out_size, void* d_ws, size_t ws_size,
                              hipStream_t stream) {
    const float* x   = (const float*)d_in[0];
    const int*   ei  = (const int*)d_in[1];
    const float* ew  = (const float*)d_in[2];
    const float* W1  = (const float*)d_in[3];
    const float* b1  = (const float*)d_in[4];
    const float* W2  = (const float*)d_in[5];
    const float* b2  = (const float*)d_in[6];
    const float* Wt1 = (const float*)d_in[7];
    const float* bt1 = (const float*)d_in[8];
    const float* Wt2 = (const float*)d_in[9];
    const float* bt2 = (const float*)d_in[10];
    float* S = (float*)d_out;  // f32 GEMM outputs live in d_out
    const int E = in_sizes[2];

    char* w = (char*)d_ws;
    float* bufA  = (float*)w;
    size_t off   = (size_t)M_ROWS * FDIM * 4;
    int* cnt     = (int*)(w + off); off += (size_t)N_NODES * 4;
    int* rowptr  = (int*)(w + off); off += (size_t)(N_NODES + 1) * 4;
    int* cursor  = (int*)(w + off); off += (size_t)N_NODES * 4;
    int* col     = (int*)(w + off); off += (size_t)E * 4;
    float* val   = (float*)(w + off); off += (size_t)E * 4;
    float* dinv  = (float*)(w + off); off += (size_t)N_NODES * 4;
    short* Wsp   = (short*)(w + off); off += (size_t)8 * FDIM * FDIM * 2;  // 4 weights x (hi,lo)
    const size_t WSZ = (size_t)FDIM * FDIM;
    short* W1h = Wsp;            short* W1l = Wsp + WSZ;
    short* W2h = Wsp + 2 * WSZ;  short* W2l = Wsp + 3 * WSZ;
    short* Wt1h = Wsp + 4 * WSZ; short* Wt1l = Wsp + 5 * WSZ;
    short* Wt2h = Wsp + 6 * WSZ; short* Wt2l = Wsp + 7 * WSZ;

    hipMemsetAsync(cnt, 0, (size_t)N_NODES * 4, stream);
    int eb = (E + 255) / 256;
    int nb = (N_NODES + 255) / 256;
    k_count<<<eb, 256, 0, stream>>>(ei, cnt, E);
    k_scan<<<1, 1024, 0, stream>>>(cnt, rowptr, cursor);
    k_fill<<<eb, 256, 0, stream>>>(ei, ew, cursor, col, val, E);
    k_dinv<<<nb, 256, 0, stream>>>(rowptr, val, dinv);
    k_scale<<<nb, 256, 0, stream>>>(rowptr, col, val, dinv);

    int wb = (FDIM * FDIM) / 256;
    k_wsplit<<<wb, 256, 0, stream>>>(W1, W1h, W1l);
    k_wsplit<<<wb, 256, 0, stream>>>(W2, W2h, W2l);
    k_wsplit<<<wb, 256, 0, stream>>>(Wt1, Wt1h, Wt1l);
    k_wsplit<<<wb, 256, 0, stream>>>(Wt2, Wt2h, Wt2l);

    int gb = (M_ROWS + 127) / 128;
    int tb = (N_NODES * FDIM + 255) / 256;

    // spatial layer 1: S = X@W1 ; bufA = relu(A*S + b1)
    k_gemm_mfma<<<gb, 256, 0, stream>>>(x, W1h, W1l, S, M_ROWS);
    k_agg12<<<N_NODES, 128, 0, stream>>>(S, rowptr, col, val, b1, bufA, 1);
    // spatial layer 2: S = bufA@W2 ; bufA = A*S + b2
    k_gemm_mfma<<<gb, 256, 0, stream>>>(bufA, W2h, W2l, S, M_ROWS);
    k_agg12<<<N_NODES, 128, 0, stream>>>(S, rowptr, col, val, b2, bufA, 0);
    // temporal layer 1: S = bufA@Wt1 ; bufA = relu(Tagg(S) + bt1)
    k_gemm_mfma<<<gb, 256, 0, stream>>>(bufA, Wt1h, Wt1l, S, M_ROWS);
    k_tagg<<<tb, 256, 0, stream>>>(S, bt1, bufA, 1);
    // temporal layer 2: S = bufA@Wt2 ; out = tanh(Tagg(S) + bt2)  (in-place on d_out)
    k_gemm_mfma<<<gb, 256, 0, stream>>>(bufA, Wt2h, Wt2l, S, M_ROWS);
    k_tagg<<<tb, 256, 0, stream>>>(S, bt2, S, 2);
}

// Round 4
// 462.753 us; speedup vs baseline: 1.4790x; 1.1401x over previous
//
#include <hip/hip_runtime.h>
#include <hip/hip_bf16.h>
#include <hip/hip_fp16.h>

#define T_STEPS 12
#define N_NODES 10000
#define FDIM 128
#define M_ROWS (T_STEPS * N_NODES)

typedef __attribute__((ext_vector_type(8))) short short8v;
typedef __attribute__((ext_vector_type(4))) float f32x4;

// ---------------- CSR build (counting sort by dst) ----------------

__global__ __launch_bounds__(256) void k_count(const int* __restrict__ ei, int* __restrict__ cnt, int E) {
    int e = blockIdx.x * 256 + threadIdx.x;
    if (e < E) atomicAdd(&cnt[ei[E + e]], 1);
}

__global__ __launch_bounds__(1024) void k_scan(const int* __restrict__ cnt, int* __restrict__ rowptr,
                                               int* __restrict__ cursor) {
    __shared__ int buf[1024];
    __shared__ int base_s;
    int tid = threadIdx.x;
    if (tid == 0) base_s = 0;
    __syncthreads();
    for (int c0 = 0; c0 < N_NODES; c0 += 1024) {
        int i = c0 + tid;
        int x = (i < N_NODES) ? cnt[i] : 0;
        buf[tid] = x;
        __syncthreads();
        for (int off = 1; off < 1024; off <<= 1) {
            int v = (tid >= off) ? buf[tid - off] : 0;
            __syncthreads();
            buf[tid] += v;
            __syncthreads();
        }
        int excl = base_s + buf[tid] - x;
        if (i < N_NODES) { rowptr[i] = excl; cursor[i] = excl; }
        __syncthreads();
        if (tid == 0) base_s = base_s + buf[1023];
        __syncthreads();
    }
    if (tid == 0) rowptr[N_NODES] = base_s;
}

__global__ __launch_bounds__(256) void k_fill(const int* __restrict__ ei, const float* __restrict__ ew,
                                              int* __restrict__ cursor, int* __restrict__ col,
                                              float* __restrict__ val, int E) {
    int e = blockIdx.x * 256 + threadIdx.x;
    if (e < E) {
        int s = ei[e];
        int d = ei[E + e];
        int slot = atomicAdd(&cursor[d], 1);
        col[slot] = s;
        val[slot] = ew[e];
    }
}

__global__ __launch_bounds__(256) void k_dinv(const int* __restrict__ rowptr, const float* __restrict__ val,
                                              float* __restrict__ dinv) {
    int n = blockIdx.x * 256 + threadIdx.x;
    if (n < N_NODES) {
        int r0 = rowptr[n], r1 = rowptr[n + 1];
        float s = 0.f;
        for (int i = r0; i < r1; ++i) s += val[i];
        dinv[n] = (s > 0.f) ? rsqrtf(s) : 0.f;
    }
}

__global__ __launch_bounds__(256) void k_scale(const int* __restrict__ rowptr, const int* __restrict__ col,
                                               float* __restrict__ val, const float* __restrict__ dinv) {
    int n = blockIdx.x * 256 + threadIdx.x;
    if (n < N_NODES) {
        int r0 = rowptr[n], r1 = rowptr[n + 1];
        float dn = dinv[n];
        for (int i = r0; i < r1; ++i) val[i] = dn * val[i] * dinv[col[i]];
    }
}

// ---------------- bf16 split helpers ----------------

__device__ __forceinline__ short bf16_rne(float x) {
    unsigned u = __builtin_bit_cast(unsigned, x);
    return (short)((u + 0x7fffu + ((u >> 16) & 1u)) >> 16);
}
__device__ __forceinline__ void split2(float x, short& hi, short& lo) {
    unsigned u = __builtin_bit_cast(unsigned, x);
    unsigned hb = (u + 0x7fffu + ((u >> 16) & 1u)) & 0xffff0000u;
    hi = (short)(hb >> 16);
    float r = x - __builtin_bit_cast(float, hb);
    lo = bf16_rne(r);
}

// Pre-split W [128k][128n] f32 -> hi/lo bf16 in MFMA B-fragment layout:
// out[((s*4+kb)*128 + col)*8 + j] = W[(s*32 + kb*8 + j)][col]
__global__ __launch_bounds__(256) void k_wsplit(const float* __restrict__ W,
                                                short* __restrict__ Whf, short* __restrict__ Wlf) {
    int idx = blockIdx.x * 256 + threadIdx.x;  // 16384
    int k = idx >> 7, col = idx & 127;
    int s = k >> 5, kb = (k >> 3) & 3, j = k & 7;
    short hi, lo;
    split2(W[(size_t)k * FDIM + col], hi, lo);
    size_t oi = (size_t)(((s * 4 + kb) * 128 + col)) * 8 + j;
    Whf[oi] = hi;
    Wlf[oi] = lo;
}

// ---------------- split-bf16 MFMA GEMM: C[M,128] = A[M,128] @ W[128,128] ----------------
// 256 threads = 4 waves; wave owns 32 rows x 128 cols (2 m-tiles x 8 n-tiles of 16x16).
// OUT_T = __half (spatial path, halves gather payload) or float (temporal path).
// C = Ahi*Whi + Ahi*Wlo + Alo*Whi  (error ~2^-17 rel).

template <typename OUT_T>
__global__ __launch_bounds__(256) void k_gemm_mfma(const float* __restrict__ A,
                                                   const short* __restrict__ Whf,
                                                   const short* __restrict__ Wlf,
                                                   OUT_T* __restrict__ C, int Mrows) {
    int tid = threadIdx.x;
    int wave = tid >> 6, lane = tid & 63;
    int lr = lane & 15, kb = lane >> 4;
    int rbase = blockIdx.x * 128 + wave * 32;

    f32x4 acc[2][8];
#pragma unroll
    for (int m = 0; m < 2; ++m)
#pragma unroll
        for (int n = 0; n < 8; ++n) acc[m][n] = (f32x4){0.f, 0.f, 0.f, 0.f};

#pragma unroll
    for (int s = 0; s < 4; ++s) {
        short8v ah[2], al[2];
#pragma unroll
        for (int m = 0; m < 2; ++m) {
            int r = rbase + m * 16 + lr;
            if (r > Mrows - 1) r = Mrows - 1;
            const float* ap = &A[(size_t)r * FDIM + s * 32 + kb * 8];
            float4 x0 = *(const float4*)ap;
            float4 x1 = *(const float4*)(ap + 4);
            float xs[8] = {x0.x, x0.y, x0.z, x0.w, x1.x, x1.y, x1.z, x1.w};
#pragma unroll
            for (int j = 0; j < 8; ++j) {
                short hi, lo;
                split2(xs[j], hi, lo);
                ah[m][j] = hi;
                al[m][j] = lo;
            }
        }
#pragma unroll
        for (int n = 0; n < 8; ++n) {
            size_t wo = (size_t)(((s * 4 + kb) * 128 + n * 16 + lr)) * 8;
            short8v wh = *(const short8v*)&Whf[wo];
            short8v wl = *(const short8v*)&Wlf[wo];
#pragma unroll
            for (int m = 0; m < 2; ++m) {
                acc[m][n] = __builtin_amdgcn_mfma_f32_16x16x32_bf16(ah[m], wh, acc[m][n], 0, 0, 0);
                acc[m][n] = __builtin_amdgcn_mfma_f32_16x16x32_bf16(ah[m], wl, acc[m][n], 0, 0, 0);
                acc[m][n] = __builtin_amdgcn_mfma_f32_16x16x32_bf16(al[m], wh, acc[m][n], 0, 0, 0);
            }
        }
    }
    // D layout: col = lane&15 (+16n), row = rbase + 16m + (lane>>4)*4 + q
#pragma unroll
    for (int m = 0; m < 2; ++m)
#pragma unroll
        for (int q = 0; q < 4; ++q) {
            int r = rbase + m * 16 + kb * 4 + q;
            if (r < Mrows) {
#pragma unroll
                for (int n = 0; n < 8; ++n)
                    C[(size_t)r * FDIM + n * 16 + lr] = (OUT_T)acc[m][n][q];
            }
        }
}

// ---------------- spatial aggregation: fp16 gather, all 12 time steps per block ----------------

__global__ __launch_bounds__(128) void k_agg12h(const __half* __restrict__ S, const int* __restrict__ rowptr,
                                                const int* __restrict__ col, const float* __restrict__ val,
                                                const float* __restrict__ bias, float* __restrict__ out,
                                                int do_relu) {
    int n = blockIdx.x;
    int c = threadIdx.x;
    int r0 = rowptr[n], r1 = rowptr[n + 1];
    float acc[T_STEPS];
#pragma unroll
    for (int t = 0; t < T_STEPS; ++t) acc[t] = 0.f;

    int i = r0;
    for (; i + 2 <= r1; i += 2) {
        int c0 = col[i], c1 = col[i + 1];
        float v0 = val[i], v1 = val[i + 1];
        const __half* S0 = S + (size_t)c0 * FDIM + c;
        const __half* S1 = S + (size_t)c1 * FDIM + c;
#pragma unroll
        for (int t = 0; t < T_STEPS; ++t) {
            float x0 = __half2float(S0[(size_t)t * N_NODES * FDIM]);
            float x1 = __half2float(S1[(size_t)t * N_NODES * FDIM]);
            acc[t] = fmaf(v0, x0, fmaf(v1, x1, acc[t]));
        }
    }
    if (i < r1) {
        int c0 = col[i];
        float v0 = val[i];
        const __half* S0 = S + (size_t)c0 * FDIM + c;
#pragma unroll
        for (int t = 0; t < T_STEPS; ++t)
            acc[t] = fmaf(v0, __half2float(S0[(size_t)t * N_NODES * FDIM]), acc[t]);
    }

    float b = bias[c];
#pragma unroll
    for (int t = 0; t < T_STEPS; ++t) {
        float o = acc[t] + b;
        if (do_relu) o = fmaxf(o, 0.f);
        out[((size_t)t * N_NODES + n) * FDIM + c] = o;
    }
}

// ---------------- temporal aggregation (chain graph, closed-form norm) ----------------

__global__ __launch_bounds__(256) void k_tagg(const float* __restrict__ S, const float* __restrict__ bias,
                                              float* __restrict__ out, int mode) {
    int idx = blockIdx.x * 256 + threadIdx.x;
    if (idx >= N_NODES * FDIM) return;
    int c = idx & (FDIM - 1);
    float s[T_STEPS];
#pragma unroll
    for (int t = 0; t < T_STEPS; ++t) s[t] = S[(size_t)t * N_NODES * FDIM + idx];
    float b = bias[c];
    const float IS2 = 0.70710678118654752f;
#pragma unroll
    for (int t = 0; t < T_STEPS; ++t) {
        float dt = (t == 0 || t == T_STEPS - 1) ? 1.f : IS2;
        float a = 0.f;
        if (t > 0) {
            float dp = (t - 1 == 0) ? 1.f : IS2;
            a += dp * s[t - 1];
        }
        if (t < T_STEPS - 1) {
            float dn = (t + 1 == T_STEPS - 1) ? 1.f : IS2;
            a += dn * s[t + 1];
        }
        float o = dt * a + b;
        if (mode == 1) o = fmaxf(o, 0.f);
        else o = tanhf(o);
        out[(size_t)t * N_NODES * FDIM + idx] = o;
    }
}

// ---------------- launch ----------------

extern "C" void kernel_launch(void* const* d_in, const int* in_sizes, int n_in,
                              void* d_out, int out_size, void* d_ws, size_t ws_size,
                              hipStream_t stream) {
    const float* x   = (const float*)d_in[0];
    const int*   ei  = (const int*)d_in[1];
    const float* ew  = (const float*)d_in[2];
    const float* W1  = (const float*)d_in[3];
    const float* b1  = (const float*)d_in[4];
    const float* W2  = (const float*)d_in[5];
    const float* b2  = (const float*)d_in[6];
    const float* Wt1 = (const float*)d_in[7];
    const float* bt1 = (const float*)d_in[8];
    const float* Wt2 = (const float*)d_in[9];
    const float* bt2 = (const float*)d_in[10];
    float*  S  = (float*)d_out;   // f32 GEMM outputs (temporal path) live in d_out
    __half* Sh = (__half*)d_out;  // fp16 GEMM outputs (spatial path) alias the same buffer
    const int E = in_sizes[2];

    char* w = (char*)d_ws;
    float* bufA  = (float*)w;
    size_t off   = (size_t)M_ROWS * FDIM * 4;
    int* cnt     = (int*)(w + off); off += (size_t)N_NODES * 4;
    int* rowptr  = (int*)(w + off); off += (size_t)(N_NODES + 1) * 4;
    int* cursor  = (int*)(w + off); off += (size_t)N_NODES * 4;
    int* col     = (int*)(w + off); off += (size_t)E * 4;
    float* val   = (float*)(w + off); off += (size_t)E * 4;
    float* dinv  = (float*)(w + off); off += (size_t)N_NODES * 4;
    short* Wsp   = (short*)(w + off); off += (size_t)8 * FDIM * FDIM * 2;  // 4 weights x (hi,lo)
    const size_t WSZ = (size_t)FDIM * FDIM;
    short* W1h = Wsp;            short* W1l = Wsp + WSZ;
    short* W2h = Wsp + 2 * WSZ;  short* W2l = Wsp + 3 * WSZ;
    short* Wt1h = Wsp + 4 * WSZ; short* Wt1l = Wsp + 5 * WSZ;
    short* Wt2h = Wsp + 6 * WSZ; short* Wt2l = Wsp + 7 * WSZ;

    hipMemsetAsync(cnt, 0, (size_t)N_NODES * 4, stream);
    int eb = (E + 255) / 256;
    int nb = (N_NODES + 255) / 256;
    k_count<<<eb, 256, 0, stream>>>(ei, cnt, E);
    k_scan<<<1, 1024, 0, stream>>>(cnt, rowptr, cursor);
    k_fill<<<eb, 256, 0, stream>>>(ei, ew, cursor, col, val, E);
    k_dinv<<<nb, 256, 0, stream>>>(rowptr, val, dinv);
    k_scale<<<nb, 256, 0, stream>>>(rowptr, col, val, dinv);

    int wb = (FDIM * FDIM) / 256;
    k_wsplit<<<wb, 256, 0, stream>>>(W1, W1h, W1l);
    k_wsplit<<<wb, 256, 0, stream>>>(W2, W2h, W2l);
    k_wsplit<<<wb, 256, 0, stream>>>(Wt1, Wt1h, Wt1l);
    k_wsplit<<<wb, 256, 0, stream>>>(Wt2, Wt2h, Wt2l);

    int gb = (M_ROWS + 127) / 128;
    int tb = (N_NODES * FDIM + 255) / 256;

    // spatial layer 1: Sh = fp16(X@W1) ; bufA = relu(A*Sh + b1)
    k_gemm_mfma<__half><<<gb, 256, 0, stream>>>(x, W1h, W1l, Sh, M_ROWS);
    k_agg12h<<<N_NODES, 128, 0, stream>>>(Sh, rowptr, col, val, b1, bufA, 1);
    // spatial layer 2: Sh = fp16(bufA@W2) ; bufA = A*Sh + b2
    k_gemm_mfma<__half><<<gb, 256, 0, stream>>>(bufA, W2h, W2l, Sh, M_ROWS);
    k_agg12h<<<N_NODES, 128, 0, stream>>>(Sh, rowptr, col, val, b2, bufA, 0);
    // temporal layer 1: S = bufA@Wt1 (f32) ; bufA = relu(Tagg(S) + bt1)
    k_gemm_mfma<float><<<gb, 256, 0, stream>>>(bufA, Wt1h, Wt1l, S, M_ROWS);
    k_tagg<<<tb, 256, 0, stream>>>(S, bt1, bufA, 1);
    // temporal layer 2: S = bufA@Wt2 (f32) ; out = tanh(Tagg(S) + bt2)  (in-place on d_out)
    k_gemm_mfma<float><<<gb, 256, 0, stream>>>(bufA, Wt2h, Wt2l, S, M_ROWS);
    k_tagg<<<tb, 256, 0, stream>>>(S, bt2, S, 2);
}

// Round 5
// 413.506 us; speedup vs baseline: 1.6551x; 1.1191x over previous
//
#include <hip/hip_runtime.h>
#include <hip/hip_bf16.h>
#include <hip/hip_fp16.h>

#define T_STEPS 12
#define N_NODES 10000
#define FDIM 128
#define M_ROWS (T_STEPS * N_NODES)

typedef __attribute__((ext_vector_type(8))) short short8v;
typedef __attribute__((ext_vector_type(4))) float f32x4;

// ---------------- CSR build (counting sort by dst) ----------------

__global__ __launch_bounds__(256) void k_count(const int* __restrict__ ei, int* __restrict__ cnt, int E) {
    int e = blockIdx.x * 256 + threadIdx.x;
    if (e < E) atomicAdd(&cnt[ei[E + e]], 1);
}

__global__ __launch_bounds__(1024) void k_scan(const int* __restrict__ cnt, int* __restrict__ rowptr,
                                               int* __restrict__ cursor) {
    __shared__ int buf[1024];
    __shared__ int base_s;
    int tid = threadIdx.x;
    if (tid == 0) base_s = 0;
    __syncthreads();
    for (int c0 = 0; c0 < N_NODES; c0 += 1024) {
        int i = c0 + tid;
        int x = (i < N_NODES) ? cnt[i] : 0;
        buf[tid] = x;
        __syncthreads();
        for (int off = 1; off < 1024; off <<= 1) {
            int v = (tid >= off) ? buf[tid - off] : 0;
            __syncthreads();
            buf[tid] += v;
            __syncthreads();
        }
        int excl = base_s + buf[tid] - x;
        if (i < N_NODES) { rowptr[i] = excl; cursor[i] = excl; }
        __syncthreads();
        if (tid == 0) base_s = base_s + buf[1023];
        __syncthreads();
    }
    if (tid == 0) rowptr[N_NODES] = base_s;
}

__global__ __launch_bounds__(256) void k_fill(const int* __restrict__ ei, const float* __restrict__ ew,
                                              int* __restrict__ cursor, int* __restrict__ col,
                                              float* __restrict__ val, int E) {
    int e = blockIdx.x * 256 + threadIdx.x;
    if (e < E) {
        int s = ei[e];
        int d = ei[E + e];
        int slot = atomicAdd(&cursor[d], 1);
        col[slot] = s;
        val[slot] = ew[e];
    }
}

__global__ __launch_bounds__(256) void k_dinv(const int* __restrict__ rowptr, const float* __restrict__ val,
                                              float* __restrict__ dinv) {
    int n = blockIdx.x * 256 + threadIdx.x;
    if (n < N_NODES) {
        int r0 = rowptr[n], r1 = rowptr[n + 1];
        float s = 0.f;
        for (int i = r0; i < r1; ++i) s += val[i];
        dinv[n] = (s > 0.f) ? rsqrtf(s) : 0.f;
    }
}

__global__ __launch_bounds__(256) void k_scale(const int* __restrict__ rowptr, const int* __restrict__ col,
                                               float* __restrict__ val, const float* __restrict__ dinv) {
    int n = blockIdx.x * 256 + threadIdx.x;
    if (n < N_NODES) {
        int r0 = rowptr[n], r1 = rowptr[n + 1];
        float dn = dinv[n];
        for (int i = r0; i < r1; ++i) val[i] = dn * val[i] * dinv[col[i]];
    }
}

// ---------------- bf16 split helpers ----------------

__device__ __forceinline__ short bf16_rne(float x) {
    unsigned u = __builtin_bit_cast(unsigned, x);
    return (short)((u + 0x7fffu + ((u >> 16) & 1u)) >> 16);
}
__device__ __forceinline__ void split2(float x, short& hi, short& lo) {
    unsigned u = __builtin_bit_cast(unsigned, x);
    unsigned hb = (u + 0x7fffu + ((u >> 16) & 1u)) & 0xffff0000u;
    hi = (short)(hb >> 16);
    float r = x - __builtin_bit_cast(float, hb);
    lo = bf16_rne(r);
}

// Pre-split W [128k][128n] f32 -> hi/lo bf16 in MFMA B-fragment layout:
// out[((s*4+kb)*128 + col)*8 + j] = W[(s*32 + kb*8 + j)][col]
__global__ __launch_bounds__(256) void k_wsplit(const float* __restrict__ W,
                                                short* __restrict__ Whf, short* __restrict__ Wlf) {
    int idx = blockIdx.x * 256 + threadIdx.x;  // 16384
    int k = idx >> 7, col = idx & 127;
    int s = k >> 5, kb = (k >> 3) & 3, j = k & 7;
    short hi, lo;
    split2(W[(size_t)k * FDIM + col], hi, lo);
    size_t oi = (size_t)(((s * 4 + kb) * 128 + col)) * 8 + j;
    Whf[oi] = hi;
    Wlf[oi] = lo;
}

// ---------------- split-bf16 MFMA GEMM: C[M,128] = A[M,128] @ W[128,128] ----------------

template <typename OUT_T>
__global__ __launch_bounds__(256) void k_gemm_mfma(const float* __restrict__ A,
                                                   const short* __restrict__ Whf,
                                                   const short* __restrict__ Wlf,
                                                   OUT_T* __restrict__ C, int Mrows) {
    int tid = threadIdx.x;
    int wave = tid >> 6, lane = tid & 63;
    int lr = lane & 15, kb = lane >> 4;
    int rbase = blockIdx.x * 128 + wave * 32;

    f32x4 acc[2][8];
#pragma unroll
    for (int m = 0; m < 2; ++m)
#pragma unroll
        for (int n = 0; n < 8; ++n) acc[m][n] = (f32x4){0.f, 0.f, 0.f, 0.f};

#pragma unroll
    for (int s = 0; s < 4; ++s) {
        short8v ah[2], al[2];
#pragma unroll
        for (int m = 0; m < 2; ++m) {
            int r = rbase + m * 16 + lr;
            if (r > Mrows - 1) r = Mrows - 1;
            const float* ap = &A[(size_t)r * FDIM + s * 32 + kb * 8];
            float4 x0 = *(const float4*)ap;
            float4 x1 = *(const float4*)(ap + 4);
            float xs[8] = {x0.x, x0.y, x0.z, x0.w, x1.x, x1.y, x1.z, x1.w};
#pragma unroll
            for (int j = 0; j < 8; ++j) {
                short hi, lo;
                split2(xs[j], hi, lo);
                ah[m][j] = hi;
                al[m][j] = lo;
            }
        }
#pragma unroll
        for (int n = 0; n < 8; ++n) {
            size_t wo = (size_t)(((s * 4 + kb) * 128 + n * 16 + lr)) * 8;
            short8v wh = *(const short8v*)&Whf[wo];
            short8v wl = *(const short8v*)&Wlf[wo];
#pragma unroll
            for (int m = 0; m < 2; ++m) {
                acc[m][n] = __builtin_amdgcn_mfma_f32_16x16x32_bf16(ah[m], wh, acc[m][n], 0, 0, 0);
                acc[m][n] = __builtin_amdgcn_mfma_f32_16x16x32_bf16(ah[m], wl, acc[m][n], 0, 0, 0);
                acc[m][n] = __builtin_amdgcn_mfma_f32_16x16x32_bf16(al[m], wh, acc[m][n], 0, 0, 0);
            }
        }
    }
#pragma unroll
    for (int m = 0; m < 2; ++m)
#pragma unroll
        for (int q = 0; q < 4; ++q) {
            int r = rbase + m * 16 + kb * 4 + q;
            if (r < Mrows) {
#pragma unroll
                for (int n = 0; n < 8; ++n)
                    C[(size_t)r * FDIM + n * 16 + lr] = (OUT_T)acc[m][n][q];
            }
        }
}

// ---------------- spatial aggregation: XCD-pinned t-slabs ----------------
// Dispatch round-robins workgroups over the 8 XCDs (bid % 8). Assign each XCD:
// full slab t=x (units 0,1) + half of slab t=8+(x/2) (unit 2) -> 1.5 slabs of
// work per XCD (balanced) and only 2 distinct t-slabs (5.12 MB) in its L2.
// Block covers 20 nodes of one t. Output stores nontemporal (don't evict slab).
// NB_HALF = 5000/20 = 250 blocks per half-slab; grid = 8 * 3 * 250 = 6000.

#define NPB 20
#define NB_HALF 250

__global__ __launch_bounds__(128) void k_aggx(const __half* __restrict__ S, const int* __restrict__ rowptr,
                                              const int* __restrict__ col, const float* __restrict__ val,
                                              const float* __restrict__ bias, float* __restrict__ out,
                                              int do_relu) {
    int bid = blockIdx.x;
    int x = bid & 7;
    int j = bid >> 3;          // 0..749
    int unit = j / NB_HALF;    // 0,1,2
    int nb = j - unit * NB_HALF;
    int t, n0;
    if (unit == 2) { t = 8 + (x >> 1); n0 = (x & 1) * 5000 + nb * NPB; }
    else           { t = x;            n0 = unit * 5000 + nb * NPB; }

    int c = threadIdx.x;
    const __half* St = S + (size_t)t * N_NODES * FDIM;
    float b = bias[c];

    for (int nn = 0; nn < NPB; ++nn) {
        int n = n0 + nn;
        int r0 = rowptr[n], r1 = rowptr[n + 1];
        float acc = 0.f;
        int i = r0;
        for (; i + 4 <= r1; i += 4) {
            int c0 = col[i], c1 = col[i + 1], c2 = col[i + 2], c3 = col[i + 3];
            float v0 = val[i], v1 = val[i + 1], v2 = val[i + 2], v3 = val[i + 3];
            float x0 = __half2float(St[(size_t)c0 * FDIM + c]);
            float x1 = __half2float(St[(size_t)c1 * FDIM + c]);
            float x2 = __half2float(St[(size_t)c2 * FDIM + c]);
            float x3 = __half2float(St[(size_t)c3 * FDIM + c]);
            acc = fmaf(v0, x0, acc);
            acc = fmaf(v1, x1, acc);
            acc = fmaf(v2, x2, acc);
            acc = fmaf(v3, x3, acc);
        }
        for (; i < r1; ++i)
            acc = fmaf(val[i], __half2float(St[(size_t)col[i] * FDIM + c]), acc);
        float o = acc + b;
        if (do_relu) o = fmaxf(o, 0.f);
        __builtin_nontemporal_store(o, &out[((size_t)t * N_NODES + n) * FDIM + c]);
    }
}

// ---------------- temporal aggregation (chain graph, closed-form norm) ----------------

__global__ __launch_bounds__(256) void k_tagg(const float* __restrict__ S, const float* __restrict__ bias,
                                              float* __restrict__ out, int mode) {
    int idx = blockIdx.x * 256 + threadIdx.x;
    if (idx >= N_NODES * FDIM) return;
    int c = idx & (FDIM - 1);
    float s[T_STEPS];
#pragma unroll
    for (int t = 0; t < T_STEPS; ++t) s[t] = S[(size_t)t * N_NODES * FDIM + idx];
    float b = bias[c];
    const float IS2 = 0.70710678118654752f;
#pragma unroll
    for (int t = 0; t < T_STEPS; ++t) {
        float dt = (t == 0 || t == T_STEPS - 1) ? 1.f : IS2;
        float a = 0.f;
        if (t > 0) {
            float dp = (t - 1 == 0) ? 1.f : IS2;
            a += dp * s[t - 1];
        }
        if (t < T_STEPS - 1) {
            float dn = (t + 1 == T_STEPS - 1) ? 1.f : IS2;
            a += dn * s[t + 1];
        }
        float o = dt * a + b;
        if (mode == 1) o = fmaxf(o, 0.f);
        else o = tanhf(o);
        out[(size_t)t * N_NODES * FDIM + idx] = o;
    }
}

// ---------------- launch ----------------

extern "C" void kernel_launch(void* const* d_in, const int* in_sizes, int n_in,
                              void* d_out, int out_size, void* d_ws, size_t ws_size,
                              hipStream_t stream) {
    const float* x   = (const float*)d_in[0];
    const int*   ei  = (const int*)d_in[1];
    const float* ew  = (const float*)d_in[2];
    const float* W1  = (const float*)d_in[3];
    const float* b1  = (const float*)d_in[4];
    const float* W2  = (const float*)d_in[5];
    const float* b2  = (const float*)d_in[6];
    const float* Wt1 = (const float*)d_in[7];
    const float* bt1 = (const float*)d_in[8];
    const float* Wt2 = (const float*)d_in[9];
    const float* bt2 = (const float*)d_in[10];
    float*  S  = (float*)d_out;   // f32 GEMM outputs (temporal path) live in d_out
    __half* Sh = (__half*)d_out;  // fp16 GEMM outputs (spatial path) alias the same buffer
    const int E = in_sizes[2];

    char* w = (char*)d_ws;
    float* bufA  = (float*)w;
    size_t off   = (size_t)M_ROWS * FDIM * 4;
    int* cnt     = (int*)(w + off); off += (size_t)N_NODES * 4;
    int* rowptr  = (int*)(w + off); off += (size_t)(N_NODES + 1) * 4;
    int* cursor  = (int*)(w + off); off += (size_t)N_NODES * 4;
    int* col     = (int*)(w + off); off += (size_t)E * 4;
    float* val   = (float*)(w + off); off += (size_t)E * 4;
    float* dinv  = (float*)(w + off); off += (size_t)N_NODES * 4;
    short* Wsp   = (short*)(w + off); off += (size_t)8 * FDIM * FDIM * 2;  // 4 weights x (hi,lo)
    const size_t WSZ = (size_t)FDIM * FDIM;
    short* W1h = Wsp;            short* W1l = Wsp + WSZ;
    short* W2h = Wsp + 2 * WSZ;  short* W2l = Wsp + 3 * WSZ;
    short* Wt1h = Wsp + 4 * WSZ; short* Wt1l = Wsp + 5 * WSZ;
    short* Wt2h = Wsp + 6 * WSZ; short* Wt2l = Wsp + 7 * WSZ;

    hipMemsetAsync(cnt, 0, (size_t)N_NODES * 4, stream);
    int eb = (E + 255) / 256;
    int nb = (N_NODES + 255) / 256;
    k_count<<<eb, 256, 0, stream>>>(ei, cnt, E);
    k_scan<<<1, 1024, 0, stream>>>(cnt, rowptr, cursor);
    k_fill<<<eb, 256, 0, stream>>>(ei, ew, cursor, col, val, E);
    k_dinv<<<nb, 256, 0, stream>>>(rowptr, val, dinv);
    k_scale<<<nb, 256, 0, stream>>>(rowptr, col, val, dinv);

    int wb = (FDIM * FDIM) / 256;
    k_wsplit<<<wb, 256, 0, stream>>>(W1, W1h, W1l);
    k_wsplit<<<wb, 256, 0, stream>>>(W2, W2h, W2l);
    k_wsplit<<<wb, 256, 0, stream>>>(Wt1, Wt1h, Wt1l);
    k_wsplit<<<wb, 256, 0, stream>>>(Wt2, Wt2h, Wt2l);

    int gb = (M_ROWS + 127) / 128;
    int tb = (N_NODES * FDIM + 255) / 256;
    int ab = 8 * 3 * NB_HALF;  // 6000 blocks, XCD-pinned decode inside

    // spatial layer 1: Sh = fp16(X@W1) ; bufA = relu(A*Sh + b1)
    k_gemm_mfma<__half><<<gb, 256, 0, stream>>>(x, W1h, W1l, Sh, M_ROWS);
    k_aggx<<<ab, 128, 0, stream>>>(Sh, rowptr, col, val, b1, bufA, 1);
    // spatial layer 2: Sh = fp16(bufA@W2) ; bufA = A*Sh + b2
    k_gemm_mfma<__half><<<gb, 256, 0, stream>>>(bufA, W2h, W2l, Sh, M_ROWS);
    k_aggx<<<ab, 128, 0, stream>>>(Sh, rowptr, col, val, b2, bufA, 0);
    // temporal layer 1: S = bufA@Wt1 (f32) ; bufA = relu(Tagg(S) + bt1)
    k_gemm_mfma<float><<<gb, 256, 0, stream>>>(bufA, Wt1h, Wt1l, S, M_ROWS);
    k_tagg<<<tb, 256, 0, stream>>>(S, bt1, bufA, 1);
    // temporal layer 2: S = bufA@Wt2 (f32) ; out = tanh(Tagg(S) + bt2)  (in-place on d_out)
    k_gemm_mfma<float><<<gb, 256, 0, stream>>>(bufA, Wt2h, Wt2l, S, M_ROWS);
    k_tagg<<<tb, 256, 0, stream>>>(S, bt2, S, 2);
}

// Round 6
// 352.784 us; speedup vs baseline: 1.9400x; 1.1721x over previous
//
#include <hip/hip_runtime.h>
#include <hip/hip_bf16.h>
#include <hip/hip_fp16.h>

#define T_STEPS 12
#define N_NODES 10000
#define FDIM 128
#define M_ROWS (T_STEPS * N_NODES)

typedef __attribute__((ext_vector_type(8))) short short8v;
typedef __attribute__((ext_vector_type(4))) float f32x4;

// ---------------- CSR build (counting sort by dst) ----------------

__global__ __launch_bounds__(256) void k_count(const int* __restrict__ ei, int* __restrict__ cnt, int E) {
    int e = blockIdx.x * 256 + threadIdx.x;
    if (e < E) atomicAdd(&cnt[ei[E + e]], 1);
}

__global__ __launch_bounds__(1024) void k_scan(const int* __restrict__ cnt, int* __restrict__ rowptr,
                                               int* __restrict__ cursor) {
    __shared__ int buf[1024];
    __shared__ int base_s;
    int tid = threadIdx.x;
    if (tid == 0) base_s = 0;
    __syncthreads();
    for (int c0 = 0; c0 < N_NODES; c0 += 1024) {
        int i = c0 + tid;
        int x = (i < N_NODES) ? cnt[i] : 0;
        buf[tid] = x;
        __syncthreads();
        for (int off = 1; off < 1024; off <<= 1) {
            int v = (tid >= off) ? buf[tid - off] : 0;
            __syncthreads();
            buf[tid] += v;
            __syncthreads();
        }
        int excl = base_s + buf[tid] - x;
        if (i < N_NODES) { rowptr[i] = excl; cursor[i] = excl; }
        __syncthreads();
        if (tid == 0) base_s = base_s + buf[1023];
        __syncthreads();
    }
    if (tid == 0) rowptr[N_NODES] = base_s;
}

__global__ __launch_bounds__(256) void k_fill(const int* __restrict__ ei, const float* __restrict__ ew,
                                              int* __restrict__ cursor, int* __restrict__ col,
                                              float* __restrict__ val, int E) {
    int e = blockIdx.x * 256 + threadIdx.x;
    if (e < E) {
        int s = ei[e];
        int d = ei[E + e];
        int slot = atomicAdd(&cursor[d], 1);
        col[slot] = s;
        val[slot] = ew[e];
    }
}

__global__ __launch_bounds__(256) void k_dinv(const int* __restrict__ rowptr, const float* __restrict__ val,
                                              float* __restrict__ dinv) {
    int n = blockIdx.x * 256 + threadIdx.x;
    if (n < N_NODES) {
        int r0 = rowptr[n], r1 = rowptr[n + 1];
        float s = 0.f;
        for (int i = r0; i < r1; ++i) s += val[i];
        dinv[n] = (s > 0.f) ? rsqrtf(s) : 0.f;
    }
}

__global__ __launch_bounds__(256) void k_scale(const int* __restrict__ rowptr, const int* __restrict__ col,
                                               float* __restrict__ val, const float* __restrict__ dinv) {
    int n = blockIdx.x * 256 + threadIdx.x;
    if (n < N_NODES) {
        int r0 = rowptr[n], r1 = rowptr[n + 1];
        float dn = dinv[n];
        for (int i = r0; i < r1; ++i) val[i] = dn * val[i] * dinv[col[i]];
    }
}

// ---------------- bf16 split helpers ----------------

__device__ __forceinline__ short bf16_rne(float x) {
    unsigned u = __builtin_bit_cast(unsigned, x);
    return (short)((u + 0x7fffu + ((u >> 16) & 1u)) >> 16);
}
__device__ __forceinline__ void split2(float x, short& hi, short& lo) {
    unsigned u = __builtin_bit_cast(unsigned, x);
    unsigned hb = (u + 0x7fffu + ((u >> 16) & 1u)) & 0xffff0000u;
    hi = (short)(hb >> 16);
    float r = x - __builtin_bit_cast(float, hb);
    lo = bf16_rne(r);
}

// Pre-split W [128k][128n] f32 -> hi/lo bf16 in MFMA B-fragment layout.
__global__ __launch_bounds__(256) void k_wsplit(const float* __restrict__ W,
                                                short* __restrict__ Whf, short* __restrict__ Wlf) {
    int idx = blockIdx.x * 256 + threadIdx.x;  // 16384
    int k = idx >> 7, col = idx & 127;
    int s = k >> 5, kb = (k >> 3) & 3, j = k & 7;
    short hi, lo;
    split2(W[(size_t)k * FDIM + col], hi, lo);
    size_t oi = (size_t)(((s * 4 + kb) * 128 + col)) * 8 + j;
    Whf[oi] = hi;
    Wlf[oi] = lo;
}

// ---------------- split-bf16 MFMA GEMM: C[M,128] = A[M,128] @ W[128,128] ----------------
// IN_T: float or __half (fp16 in-register -> exact bf16 hi/lo split).
// OUT_T: __half (intermediates) or float.

template <typename IN_T, typename OUT_T>
__global__ __launch_bounds__(256) void k_gemm_mfma(const IN_T* __restrict__ A,
                                                   const short* __restrict__ Whf,
                                                   const short* __restrict__ Wlf,
                                                   OUT_T* __restrict__ C, int Mrows) {
    int tid = threadIdx.x;
    int wave = tid >> 6, lane = tid & 63;
    int lr = lane & 15, kb = lane >> 4;
    int rbase = blockIdx.x * 128 + wave * 32;

    f32x4 acc[2][8];
#pragma unroll
    for (int m = 0; m < 2; ++m)
#pragma unroll
        for (int n = 0; n < 8; ++n) acc[m][n] = (f32x4){0.f, 0.f, 0.f, 0.f};

#pragma unroll
    for (int s = 0; s < 4; ++s) {
        short8v ah[2], al[2];
#pragma unroll
        for (int m = 0; m < 2; ++m) {
            int r = rbase + m * 16 + lr;
            if (r > Mrows - 1) r = Mrows - 1;
            const IN_T* ap = &A[(size_t)r * FDIM + s * 32 + kb * 8];
            float xs[8];
            if constexpr (sizeof(IN_T) == 4) {
                float4 x0 = *(const float4*)ap;
                float4 x1 = *(const float4*)(ap + 4);
                xs[0] = x0.x; xs[1] = x0.y; xs[2] = x0.z; xs[3] = x0.w;
                xs[4] = x1.x; xs[5] = x1.y; xs[6] = x1.z; xs[7] = x1.w;
            } else {
                short8v raw = *(const short8v*)ap;
#pragma unroll
                for (int j = 0; j < 8; ++j)
                    xs[j] = __half2float(__builtin_bit_cast(__half, (short)raw[j]));
            }
#pragma unroll
            for (int j = 0; j < 8; ++j) {
                short hi, lo;
                split2(xs[j], hi, lo);
                ah[m][j] = hi;
                al[m][j] = lo;
            }
        }
#pragma unroll
        for (int n = 0; n < 8; ++n) {
            size_t wo = (size_t)(((s * 4 + kb) * 128 + n * 16 + lr)) * 8;
            short8v wh = *(const short8v*)&Whf[wo];
            short8v wl = *(const short8v*)&Wlf[wo];
#pragma unroll
            for (int m = 0; m < 2; ++m) {
                acc[m][n] = __builtin_amdgcn_mfma_f32_16x16x32_bf16(ah[m], wh, acc[m][n], 0, 0, 0);
                acc[m][n] = __builtin_amdgcn_mfma_f32_16x16x32_bf16(ah[m], wl, acc[m][n], 0, 0, 0);
                acc[m][n] = __builtin_amdgcn_mfma_f32_16x16x32_bf16(al[m], wh, acc[m][n], 0, 0, 0);
            }
        }
    }
#pragma unroll
    for (int m = 0; m < 2; ++m)
#pragma unroll
        for (int q = 0; q < 4; ++q) {
            int r = rbase + m * 16 + kb * 4 + q;
            if (r < Mrows) {
#pragma unroll
                for (int n = 0; n < 8; ++n)
                    C[(size_t)r * FDIM + n * 16 + lr] = (OUT_T)acc[m][n][q];
            }
        }
}

// ---------------- spatial aggregation: XCD-pinned t-slabs, half2 gathers ----------------
// XCD x (bid%8) owns slab t=x + half of slab t=8+(x/2); block covers 20 nodes;
// the 2 waves split the NODES (10 each); each lane gathers a __half2 (features
// 2*lane, 2*lane+1) so ONE wave-instr covers a full 256-B row per edge.

#define NPB 20
#define NB_HALF 250

__global__ __launch_bounds__(128) void k_aggx(const __half2* __restrict__ S2, const int* __restrict__ rowptr,
                                              const int* __restrict__ col, const float* __restrict__ val,
                                              const float* __restrict__ bias, __half* __restrict__ out,
                                              int do_relu) {
    int bid = blockIdx.x;
    int x = bid & 7;
    int j = bid >> 3;          // 0..749
    int unit = j / NB_HALF;    // 0,1,2
    int nb = j - unit * NB_HALF;
    int t, n0;
    if (unit == 2) { t = 8 + (x >> 1); n0 = (x & 1) * 5000 + nb * NPB; }
    else           { t = x;            n0 = unit * 5000 + nb * NPB; }

    int wave = threadIdx.x >> 6, lane = threadIdx.x & 63;
    const __half2* St = S2 + (size_t)t * N_NODES * 64;
    float b0 = bias[2 * lane], b1 = bias[2 * lane + 1];

    for (int nn = 0; nn < NPB / 2; ++nn) {
        int n = n0 + wave * (NPB / 2) + nn;
        int r0 = rowptr[n], r1 = rowptr[n + 1];
        float a0 = 0.f, a1 = 0.f;
        int i = r0;
        for (; i + 4 <= r1; i += 4) {
            int c0 = col[i], c1 = col[i + 1], c2 = col[i + 2], c3 = col[i + 3];
            float v0 = val[i], v1 = val[i + 1], v2 = val[i + 2], v3 = val[i + 3];
            float2 f0 = __half22float2(St[(size_t)c0 * 64 + lane]);
            float2 f1 = __half22float2(St[(size_t)c1 * 64 + lane]);
            float2 f2 = __half22float2(St[(size_t)c2 * 64 + lane]);
            float2 f3 = __half22float2(St[(size_t)c3 * 64 + lane]);
            a0 = fmaf(v0, f0.x, a0); a1 = fmaf(v0, f0.y, a1);
            a0 = fmaf(v1, f1.x, a0); a1 = fmaf(v1, f1.y, a1);
            a0 = fmaf(v2, f2.x, a0); a1 = fmaf(v2, f2.y, a1);
            a0 = fmaf(v3, f3.x, a0); a1 = fmaf(v3, f3.y, a1);
        }
        for (; i < r1; ++i) {
            float v = val[i];
            float2 f = __half22float2(St[(size_t)col[i] * 64 + lane]);
            a0 = fmaf(v, f.x, a0); a1 = fmaf(v, f.y, a1);
        }
        float o0 = a0 + b0, o1 = a1 + b1;
        if (do_relu) { o0 = fmaxf(o0, 0.f); o1 = fmaxf(o1, 0.f); }
        __half2 h = __floats2half2_rn(o0, o1);
        unsigned u = __builtin_bit_cast(unsigned, h);
        __builtin_nontemporal_store(u, (unsigned*)&out[((size_t)t * N_NODES + n) * FDIM + 2 * lane]);
    }
}

// ---------------- temporal aggregation (chain graph, closed-form norm), fp16 I/O ----------------

__device__ __forceinline__ void tagg_core(float2 (&s)[T_STEPS], float b0, float b1,
                                          float2 (&o)[T_STEPS]) {
    const float IS2 = 0.70710678118654752f;
#pragma unroll
    for (int t = 0; t < T_STEPS; ++t) {
        float dt = (t == 0 || t == T_STEPS - 1) ? 1.f : IS2;
        float a0 = 0.f, a1 = 0.f;
        if (t > 0) {
            float dp = (t - 1 == 0) ? 1.f : IS2;
            a0 += dp * s[t - 1].x; a1 += dp * s[t - 1].y;
        }
        if (t < T_STEPS - 1) {
            float dn = (t + 1 == T_STEPS - 1) ? 1.f : IS2;
            a0 += dn * s[t + 1].x; a1 += dn * s[t + 1].y;
        }
        o[t].x = dt * a0 + b0;
        o[t].y = dt * a1 + b1;
    }
}

__global__ __launch_bounds__(256) void k_tagg_relu(const __half2* __restrict__ S2,
                                                   const float* __restrict__ bias,
                                                   __half2* __restrict__ out) {
    int p = blockIdx.x * 256 + threadIdx.x;
    if (p >= N_NODES * 64) return;
    int c2 = p & 63;
    float b0 = bias[2 * c2], b1 = bias[2 * c2 + 1];
    float2 s[T_STEPS], o[T_STEPS];
#pragma unroll
    for (int t = 0; t < T_STEPS; ++t) s[t] = __half22float2(S2[(size_t)t * N_NODES * 64 + p]);
    tagg_core(s, b0, b1, o);
#pragma unroll
    for (int t = 0; t < T_STEPS; ++t) {
        float o0 = fmaxf(o[t].x, 0.f), o1 = fmaxf(o[t].y, 0.f);
        out[(size_t)t * N_NODES * 64 + p] = __floats2half2_rn(o0, o1);
    }
}

__global__ __launch_bounds__(256) void k_tagg_tanh(const __half2* __restrict__ S2,
                                                   const float* __restrict__ bias,
                                                   float* __restrict__ out) {
    int p = blockIdx.x * 256 + threadIdx.x;
    if (p >= N_NODES * 64) return;
    int c2 = p & 63;
    float b0 = bias[2 * c2], b1 = bias[2 * c2 + 1];
    float2 s[T_STEPS], o[T_STEPS];
#pragma unroll
    for (int t = 0; t < T_STEPS; ++t) s[t] = __half22float2(S2[(size_t)t * N_NODES * 64 + p]);
    tagg_core(s, b0, b1, o);
#pragma unroll
    for (int t = 0; t < T_STEPS; ++t) {
        float2 r = make_float2(tanhf(o[t].x), tanhf(o[t].y));
        *(float2*)&out[(size_t)t * N_NODES * FDIM + 2 * (size_t)p] = r;
    }
}

// ---------------- launch ----------------

extern "C" void kernel_launch(void* const* d_in, const int* in_sizes, int n_in,
                              void* d_out, int out_size, void* d_ws, size_t ws_size,
                              hipStream_t stream) {
    const float* x   = (const float*)d_in[0];
    const int*   ei  = (const int*)d_in[1];
    const float* ew  = (const float*)d_in[2];
    const float* W1  = (const float*)d_in[3];
    const float* b1  = (const float*)d_in[4];
    const float* W2  = (const float*)d_in[5];
    const float* b2  = (const float*)d_in[6];
    const float* Wt1 = (const float*)d_in[7];
    const float* bt1 = (const float*)d_in[8];
    const float* Wt2 = (const float*)d_in[9];
    const float* bt2 = (const float*)d_in[10];
    float*  outF = (float*)d_out;
    __half* Sh   = (__half*)d_out;  // fp16 GEMM outputs alias front half of d_out
    const int E = in_sizes[2];

    char* w = (char*)d_ws;
    __half* bufH = (__half*)w;                 // fp16 agg/tagg outputs (GEMM A inputs)
    size_t off   = (size_t)M_ROWS * FDIM * 2;
    __half* S2h  = (__half*)(w + off); off += (size_t)M_ROWS * FDIM * 2;  // last GEMM out
    int* cnt     = (int*)(w + off); off += (size_t)N_NODES * 4;
    int* rowptr  = (int*)(w + off); off += (size_t)(N_NODES + 1) * 4;
    int* cursor  = (int*)(w + off); off += (size_t)N_NODES * 4;
    int* col     = (int*)(w + off); off += (size_t)E * 4;
    float* val   = (float*)(w + off); off += (size_t)E * 4;
    float* dinv  = (float*)(w + off); off += (size_t)N_NODES * 4;
    short* Wsp   = (short*)(w + off); off += (size_t)8 * FDIM * FDIM * 2;
    const size_t WSZ = (size_t)FDIM * FDIM;
    short* W1h = Wsp;            short* W1l = Wsp + WSZ;
    short* W2h = Wsp + 2 * WSZ;  short* W2l = Wsp + 3 * WSZ;
    short* Wt1h = Wsp + 4 * WSZ; short* Wt1l = Wsp + 5 * WSZ;
    short* Wt2h = Wsp + 6 * WSZ; short* Wt2l = Wsp + 7 * WSZ;

    hipMemsetAsync(cnt, 0, (size_t)N_NODES * 4, stream);
    int eb = (E + 255) / 256;
    int nb = (N_NODES + 255) / 256;
    k_count<<<eb, 256, 0, stream>>>(ei, cnt, E);
    k_scan<<<1, 1024, 0, stream>>>(cnt, rowptr, cursor);
    k_fill<<<eb, 256, 0, stream>>>(ei, ew, cursor, col, val, E);
    k_dinv<<<nb, 256, 0, stream>>>(rowptr, val, dinv);
    k_scale<<<nb, 256, 0, stream>>>(rowptr, col, val, dinv);

    int wb = (FDIM * FDIM) / 256;
    k_wsplit<<<wb, 256, 0, stream>>>(W1, W1h, W1l);
    k_wsplit<<<wb, 256, 0, stream>>>(W2, W2h, W2l);
    k_wsplit<<<wb, 256, 0, stream>>>(Wt1, Wt1h, Wt1l);
    k_wsplit<<<wb, 256, 0, stream>>>(Wt2, Wt2h, Wt2l);

    int gb = (M_ROWS + 127) / 128;
    int tb = (N_NODES * 64 + 255) / 256;
    int ab = 8 * 3 * NB_HALF;  // 6000 blocks, XCD-pinned decode inside

    // spatial layer 1: Sh = fp16(X@W1) ; bufH = fp16(relu(A*Sh + b1))
    k_gemm_mfma<float, __half><<<gb, 256, 0, stream>>>(x, W1h, W1l, Sh, M_ROWS);
    k_aggx<<<ab, 128, 0, stream>>>((const __half2*)Sh, rowptr, col, val, b1, bufH, 1);
    // spatial layer 2
    k_gemm_mfma<__half, __half><<<gb, 256, 0, stream>>>(bufH, W2h, W2l, Sh, M_ROWS);
    k_aggx<<<ab, 128, 0, stream>>>((const __half2*)Sh, rowptr, col, val, b2, bufH, 0);
    // temporal layer 1: Sh = fp16(bufH@Wt1) ; bufH = fp16(relu(Tagg(Sh)+bt1))
    k_gemm_mfma<__half, __half><<<gb, 256, 0, stream>>>(bufH, Wt1h, Wt1l, Sh, M_ROWS);
    k_tagg_relu<<<tb, 256, 0, stream>>>((const __half2*)Sh, bt1, (__half2*)bufH);
    // temporal layer 2: S2h = fp16(bufH@Wt2) ; out = tanh(Tagg(S2h)+bt2)  (f32 to d_out)
    k_gemm_mfma<__half, __half><<<gb, 256, 0, stream>>>(bufH, Wt2h, Wt2l, S2h, M_ROWS);
    k_tagg_tanh<<<tb, 256, 0, stream>>>((const __half2*)S2h, bt2, outF);
}

// Round 7
// 340.509 us; speedup vs baseline: 2.0099x; 1.0360x over previous
//
#include <hip/hip_runtime.h>
#include <hip/hip_bf16.h>
#include <hip/hip_fp16.h>

#define T_STEPS 12
#define N_NODES 10000
#define FDIM 128
#define M_ROWS (T_STEPS * N_NODES)

typedef __attribute__((ext_vector_type(8))) short short8v;
typedef __attribute__((ext_vector_type(8))) _Float16 half8v;
typedef __attribute__((ext_vector_type(4))) float f32x4;

// ---------------- CSR build (counting sort by dst) ----------------

__global__ __launch_bounds__(256) void k_count(const int* __restrict__ ei, int* __restrict__ cnt, int E) {
    int e = blockIdx.x * 256 + threadIdx.x;
    if (e < E) atomicAdd(&cnt[ei[E + e]], 1);
}

__global__ __launch_bounds__(1024) void k_scan(const int* __restrict__ cnt, int* __restrict__ rowptr,
                                               int* __restrict__ cursor) {
    __shared__ int buf[1024];
    __shared__ int base_s;
    int tid = threadIdx.x;
    if (tid == 0) base_s = 0;
    __syncthreads();
    for (int c0 = 0; c0 < N_NODES; c0 += 1024) {
        int i = c0 + tid;
        int x = (i < N_NODES) ? cnt[i] : 0;
        buf[tid] = x;
        __syncthreads();
        for (int off = 1; off < 1024; off <<= 1) {
            int v = (tid >= off) ? buf[tid - off] : 0;
            __syncthreads();
            buf[tid] += v;
            __syncthreads();
        }
        int excl = base_s + buf[tid] - x;
        if (i < N_NODES) { rowptr[i] = excl; cursor[i] = excl; }
        __syncthreads();
        if (tid == 0) base_s = base_s + buf[1023];
        __syncthreads();
    }
    if (tid == 0) rowptr[N_NODES] = base_s;
}

__global__ __launch_bounds__(256) void k_fill(const int* __restrict__ ei, const float* __restrict__ ew,
                                              int* __restrict__ cursor, int* __restrict__ col,
                                              float* __restrict__ val, int E) {
    int e = blockIdx.x * 256 + threadIdx.x;
    if (e < E) {
        int s = ei[e];
        int d = ei[E + e];
        int slot = atomicAdd(&cursor[d], 1);
        col[slot] = s;
        val[slot] = ew[e];
    }
}

__global__ __launch_bounds__(256) void k_dinv(const int* __restrict__ rowptr, const float* __restrict__ val,
                                              float* __restrict__ dinv) {
    int n = blockIdx.x * 256 + threadIdx.x;
    if (n < N_NODES) {
        int r0 = rowptr[n], r1 = rowptr[n + 1];
        float s = 0.f;
        for (int i = r0; i < r1; ++i) s += val[i];
        dinv[n] = (s > 0.f) ? rsqrtf(s) : 0.f;
    }
}

__global__ __launch_bounds__(256) void k_scale(const int* __restrict__ rowptr, const int* __restrict__ col,
                                               float* __restrict__ val, const float* __restrict__ dinv) {
    int n = blockIdx.x * 256 + threadIdx.x;
    if (n < N_NODES) {
        int r0 = rowptr[n], r1 = rowptr[n + 1];
        float dn = dinv[n];
        for (int i = r0; i < r1; ++i) val[i] = dn * val[i] * dinv[col[i]];
    }
}

// ---------------- W pre-split: f32 -> fp16 hi + fp16 lo in MFMA B-frag layout ----------------
// frag index: out[((s*4+kb)*128 + col)*8 + j] = W[(s*32 + kb*8 + j)][col]
// W ~= Whi + Wlo to ~2^-19 (Wlo may be fp16-denormal; even if flushed, error ~2^-12 rel).

__global__ __launch_bounds__(256) void k_wsplit4(const float* __restrict__ Wa, const float* __restrict__ Wb,
                                                 const float* __restrict__ Wc, const float* __restrict__ Wd,
                                                 short* __restrict__ base) {
    int wsel = blockIdx.y;
    const float* W = (wsel == 0) ? Wa : (wsel == 1) ? Wb : (wsel == 2) ? Wc : Wd;
    short* Whf = base + (size_t)wsel * 2 * FDIM * FDIM;
    short* Wlf = Whf + FDIM * FDIM;
    int idx = blockIdx.x * 256 + threadIdx.x;  // 16384
    int k = idx >> 7, col = idx & 127;
    int s = k >> 5, kb = (k >> 3) & 3, j = k & 7;
    float w = W[(size_t)k * FDIM + col];
    _Float16 hi = (_Float16)w;
    _Float16 lo = (_Float16)(w - (float)hi);
    size_t oi = (size_t)(((s * 4 + kb) * 128 + col)) * 8 + j;
    Whf[oi] = __builtin_bit_cast(short, hi);
    Wlf[oi] = __builtin_bit_cast(short, lo);
}

// ---------------- fp16 MFMA GEMM: C[M,128] = A[M,128] @ (Whi+Wlo) ----------------
// 256 threads = 4 waves; wave owns 32 rows x 128 cols (2 m x 8 n tiles of 16x16).
// A is fp16 (exact) or f32 converted to fp16 in-register (layer 1 only).
// 2 MFMA terms per (m,n,s): A*Whi + A*Wlo. No split VALU in the hot loop.

template <typename IN_T, typename OUT_T>
__global__ __launch_bounds__(256) void k_gemm_f16(const IN_T* __restrict__ A,
                                                  const short* __restrict__ Whf,
                                                  const short* __restrict__ Wlf,
                                                  OUT_T* __restrict__ C, int Mrows) {
    int tid = threadIdx.x;
    int wave = tid >> 6, lane = tid & 63;
    int lr = lane & 15, kb = lane >> 4;
    int rbase = blockIdx.x * 128 + wave * 32;

    f32x4 acc[2][8];
#pragma unroll
    for (int m = 0; m < 2; ++m)
#pragma unroll
        for (int n = 0; n < 8; ++n) acc[m][n] = (f32x4){0.f, 0.f, 0.f, 0.f};

#pragma unroll
    for (int s = 0; s < 4; ++s) {
        half8v a[2];
#pragma unroll
        for (int m = 0; m < 2; ++m) {
            int r = rbase + m * 16 + lr;
            if (r > Mrows - 1) r = Mrows - 1;
            const IN_T* ap = &A[(size_t)r * FDIM + s * 32 + kb * 8];
            if constexpr (sizeof(IN_T) == 4) {
                float4 x0 = *(const float4*)ap;
                float4 x1 = *(const float4*)(ap + 4);
                a[m][0] = (_Float16)x0.x; a[m][1] = (_Float16)x0.y;
                a[m][2] = (_Float16)x0.z; a[m][3] = (_Float16)x0.w;
                a[m][4] = (_Float16)x1.x; a[m][5] = (_Float16)x1.y;
                a[m][6] = (_Float16)x1.z; a[m][7] = (_Float16)x1.w;
            } else {
                a[m] = __builtin_bit_cast(half8v, *(const short8v*)ap);
            }
        }
#pragma unroll
        for (int n = 0; n < 8; ++n) {
            size_t wo = (size_t)(((s * 4 + kb) * 128 + n * 16 + lr)) * 8;
            half8v wh = __builtin_bit_cast(half8v, *(const short8v*)&Whf[wo]);
            half8v wl = __builtin_bit_cast(half8v, *(const short8v*)&Wlf[wo]);
#pragma unroll
            for (int m = 0; m < 2; ++m) {
                acc[m][n] = __builtin_amdgcn_mfma_f32_16x16x32_f16(a[m], wh, acc[m][n], 0, 0, 0);
                acc[m][n] = __builtin_amdgcn_mfma_f32_16x16x32_f16(a[m], wl, acc[m][n], 0, 0, 0);
            }
        }
    }
    // D layout: col = lane&15 (+16n), row = rbase + 16m + (lane>>4)*4 + q
#pragma unroll
    for (int m = 0; m < 2; ++m)
#pragma unroll
        for (int q = 0; q < 4; ++q) {
            int r = rbase + m * 16 + kb * 4 + q;
            if (r < Mrows) {
#pragma unroll
                for (int n = 0; n < 8; ++n)
                    C[(size_t)r * FDIM + n * 16 + lr] = (OUT_T)acc[m][n][q];
            }
        }
}

// ---------------- spatial aggregation: XCD-pinned t-slabs, half2 gathers, 8-deep MLP ----------------

#define NPB 20
#define NB_HALF 250

__global__ __launch_bounds__(128) void k_aggx(const __half2* __restrict__ S2, const int* __restrict__ rowptr,
                                              const int* __restrict__ col, const float* __restrict__ val,
                                              const float* __restrict__ bias, __half* __restrict__ out,
                                              int do_relu) {
    int bid = blockIdx.x;
    int x = bid & 7;
    int j = bid >> 3;          // 0..749
    int unit = j / NB_HALF;    // 0,1,2
    int nb = j - unit * NB_HALF;
    int t, n0;
    if (unit == 2) { t = 8 + (x >> 1); n0 = (x & 1) * 5000 + nb * NPB; }
    else           { t = x;            n0 = unit * 5000 + nb * NPB; }

    int wave = threadIdx.x >> 6, lane = threadIdx.x & 63;
    const __half2* St = S2 + (size_t)t * N_NODES * 64;
    float b0 = bias[2 * lane], b1 = bias[2 * lane + 1];

    for (int nn = 0; nn < NPB / 2; ++nn) {
        int n = n0 + wave * (NPB / 2) + nn;
        int r0 = rowptr[n], r1 = rowptr[n + 1];
        float a0 = 0.f, a1 = 0.f;
        int i = r0;
        for (; i + 8 <= r1; i += 8) {
            int cc[8]; float vv[8];
#pragma unroll
            for (int q = 0; q < 8; ++q) { cc[q] = col[i + q]; vv[q] = val[i + q]; }
            float2 f[8];
#pragma unroll
            for (int q = 0; q < 8; ++q) f[q] = __half22float2(St[(size_t)cc[q] * 64 + lane]);
#pragma unroll
            for (int q = 0; q < 8; ++q) { a0 = fmaf(vv[q], f[q].x, a0); a1 = fmaf(vv[q], f[q].y, a1); }
        }
        for (; i + 4 <= r1; i += 4) {
            int cc[4]; float vv[4];
#pragma unroll
            for (int q = 0; q < 4; ++q) { cc[q] = col[i + q]; vv[q] = val[i + q]; }
            float2 f[4];
#pragma unroll
            for (int q = 0; q < 4; ++q) f[q] = __half22float2(St[(size_t)cc[q] * 64 + lane]);
#pragma unroll
            for (int q = 0; q < 4; ++q) { a0 = fmaf(vv[q], f[q].x, a0); a1 = fmaf(vv[q], f[q].y, a1); }
        }
        for (; i < r1; ++i) {
            float v = val[i];
            float2 f = __half22float2(St[(size_t)col[i] * 64 + lane]);
            a0 = fmaf(v, f.x, a0); a1 = fmaf(v, f.y, a1);
        }
        float o0 = a0 + b0, o1 = a1 + b1;
        if (do_relu) { o0 = fmaxf(o0, 0.f); o1 = fmaxf(o1, 0.f); }
        __half2 h = __floats2half2_rn(o0, o1);
        unsigned u = __builtin_bit_cast(unsigned, h);
        __builtin_nontemporal_store(u, (unsigned*)&out[((size_t)t * N_NODES + n) * FDIM + 2 * lane]);
    }
}

// ---------------- temporal aggregation (chain graph, closed-form norm), fp16 I/O ----------------

__device__ __forceinline__ void tagg_core(float2 (&s)[T_STEPS], float b0, float b1,
                                          float2 (&o)[T_STEPS]) {
    const float IS2 = 0.70710678118654752f;
#pragma unroll
    for (int t = 0; t < T_STEPS; ++t) {
        float dt = (t == 0 || t == T_STEPS - 1) ? 1.f : IS2;
        float a0 = 0.f, a1 = 0.f;
        if (t > 0) {
            float dp = (t - 1 == 0) ? 1.f : IS2;
            a0 += dp * s[t - 1].x; a1 += dp * s[t - 1].y;
        }
        if (t < T_STEPS - 1) {
            float dn = (t + 1 == T_STEPS - 1) ? 1.f : IS2;
            a0 += dn * s[t + 1].x; a1 += dn * s[t + 1].y;
        }
        o[t].x = dt * a0 + b0;
        o[t].y = dt * a1 + b1;
    }
}

__global__ __launch_bounds__(256) void k_tagg_relu(const __half2* __restrict__ S2,
                                                   const float* __restrict__ bias,
                                                   __half2* __restrict__ out) {
    int p = blockIdx.x * 256 + threadIdx.x;
    if (p >= N_NODES * 64) return;
    int c2 = p & 63;
    float b0 = bias[2 * c2], b1 = bias[2 * c2 + 1];
    float2 s[T_STEPS], o[T_STEPS];
#pragma unroll
    for (int t = 0; t < T_STEPS; ++t) s[t] = __half22float2(S2[(size_t)t * N_NODES * 64 + p]);
    tagg_core(s, b0, b1, o);
#pragma unroll
    for (int t = 0; t < T_STEPS; ++t) {
        float o0 = fmaxf(o[t].x, 0.f), o1 = fmaxf(o[t].y, 0.f);
        out[(size_t)t * N_NODES * 64 + p] = __floats2half2_rn(o0, o1);
    }
}

__global__ __launch_bounds__(256) void k_tagg_tanh(const __half2* __restrict__ S2,
                                                   const float* __restrict__ bias,
                                                   float* __restrict__ out) {
    int p = blockIdx.x * 256 + threadIdx.x;
    if (p >= N_NODES * 64) return;
    int c2 = p & 63;
    float b0 = bias[2 * c2], b1 = bias[2 * c2 + 1];
    float2 s[T_STEPS], o[T_STEPS];
#pragma unroll
    for (int t = 0; t < T_STEPS; ++t) s[t] = __half22float2(S2[(size_t)t * N_NODES * 64 + p]);
    tagg_core(s, b0, b1, o);
#pragma unroll
    for (int t = 0; t < T_STEPS; ++t) {
        float2 r = make_float2(tanhf(o[t].x), tanhf(o[t].y));
        *(float2*)&out[(size_t)t * N_NODES * FDIM + 2 * (size_t)p] = r;
    }
}

// ---------------- launch ----------------

extern "C" void kernel_launch(void* const* d_in, const int* in_sizes, int n_in,
                              void* d_out, int out_size, void* d_ws, size_t ws_size,
                              hipStream_t stream) {
    const float* x   = (const float*)d_in[0];
    const int*   ei  = (const int*)d_in[1];
    const float* ew  = (const float*)d_in[2];
    const float* W1  = (const float*)d_in[3];
    const float* b1  = (const float*)d_in[4];
    const float* W2  = (const float*)d_in[5];
    const float* b2  = (const float*)d_in[6];
    const float* Wt1 = (const float*)d_in[7];
    const float* bt1 = (const float*)d_in[8];
    const float* Wt2 = (const float*)d_in[9];
    const float* bt2 = (const float*)d_in[10];
    float*  outF = (float*)d_out;
    __half* Sh   = (__half*)d_out;  // fp16 GEMM outputs alias front half of d_out
    const int E = in_sizes[2];

    char* w = (char*)d_ws;
    __half* bufH = (__half*)w;                 // fp16 agg/tagg outputs (GEMM A inputs)
    size_t off   = (size_t)M_ROWS * FDIM * 2;
    __half* S2h  = (__half*)(w + off); off += (size_t)M_ROWS * FDIM * 2;  // last GEMM out
    int* cnt     = (int*)(w + off); off += (size_t)N_NODES * 4;
    int* rowptr  = (int*)(w + off); off += (size_t)(N_NODES + 1) * 4;
    int* cursor  = (int*)(w + off); off += (size_t)N_NODES * 4;
    int* col     = (int*)(w + off); off += (size_t)E * 4;
    float* val   = (float*)(w + off); off += (size_t)E * 4;
    float* dinv  = (float*)(w + off); off += (size_t)N_NODES * 4;
    short* Wsp   = (short*)(w + off); off += (size_t)8 * FDIM * FDIM * 2;  // 4 x (hi,lo)
    const size_t WSZ = (size_t)FDIM * FDIM;
    short* W1h = Wsp;            short* W1l = Wsp + WSZ;
    short* W2h = Wsp + 2 * WSZ;  short* W2l = Wsp + 3 * WSZ;
    short* Wt1h = Wsp + 4 * WSZ; short* Wt1l = Wsp + 5 * WSZ;
    short* Wt2h = Wsp + 6 * WSZ; short* Wt2l = Wsp + 7 * WSZ;

    hipMemsetAsync(cnt, 0, (size_t)N_NODES * 4, stream);
    int eb = (E + 255) / 256;
    int nb = (N_NODES + 255) / 256;
    k_count<<<eb, 256, 0, stream>>>(ei, cnt, E);
    k_scan<<<1, 1024, 0, stream>>>(cnt, rowptr, cursor);
    k_fill<<<eb, 256, 0, stream>>>(ei, ew, cursor, col, val, E);
    k_dinv<<<nb, 256, 0, stream>>>(rowptr, val, dinv);
    k_scale<<<nb, 256, 0, stream>>>(rowptr, col, val, dinv);

    dim3 wgrid((FDIM * FDIM) / 256, 4);
    k_wsplit4<<<wgrid, 256, 0, stream>>>(W1, W2, Wt1, Wt2, Wsp);

    int gb = (M_ROWS + 127) / 128;
    int tb = (N_NODES * 64 + 255) / 256;
    int ab = 8 * 3 * NB_HALF;  // 6000 blocks, XCD-pinned decode inside

    // spatial layer 1: Sh = fp16(X@W1) ; bufH = fp16(relu(A*Sh + b1))
    k_gemm_f16<float, __half><<<gb, 256, 0, stream>>>(x, W1h, W1l, Sh, M_ROWS);
    k_aggx<<<ab, 128, 0, stream>>>((const __half2*)Sh, rowptr, col, val, b1, bufH, 1);
    // spatial layer 2
    k_gemm_f16<__half, __half><<<gb, 256, 0, stream>>>(bufH, W2h, W2l, Sh, M_ROWS);
    k_aggx<<<ab, 128, 0, stream>>>((const __half2*)Sh, rowptr, col, val, b2, bufH, 0);
    // temporal layer 1: Sh = fp16(bufH@Wt1) ; bufH = fp16(relu(Tagg(Sh)+bt1))
    k_gemm_f16<__half, __half><<<gb, 256, 0, stream>>>(bufH, Wt1h, Wt1l, Sh, M_ROWS);
    k_tagg_relu<<<tb, 256, 0, stream>>>((const __half2*)Sh, bt1, (__half2*)bufH);
    // temporal layer 2: S2h = fp16(bufH@Wt2) ; out = tanh(Tagg(S2h)+bt2)  (f32 to d_out)
    k_gemm_f16<__half, __half><<<gb, 256, 0, stream>>>(bufH, Wt2h, Wt2l, S2h, M_ROWS);
    k_tagg_tanh<<<tb, 256, 0, stream>>>((const __half2*)S2h, bt2, outF);
}